// Round 4
// baseline (106.498 us; speedup 1.0000x reference)
//
#include <hip/hip_runtime.h>
#include <hip/hip_bf16.h>

// BasicBlock9: B=16, CIN=CP=64, H=W=64, K1=3 (deform), K2=5, EPS=1e-5
// R18: fused kernel DE-STAGED. The LDS x-tile was a copy of xT costing:
//   42% of CU cycles on the LDS pipe (36K read + 14K conflict cyc/CU),
//   52KB/block residency (occupancy wall), and barrier lockstep.
//   Now B-frags are read directly from halo-padded xTp (cols -2..65
//   zeroed; bf16 cin-contiguous 16B frags, L2-resident, 4-ks reads per
//   pixel cover one 128B line -> L1 line locality). Deform single path
//   (clamped global reads). 1-row blocks (64,16)=1024 = 4 blocks/CU all
//   resident (LDS 22KB) -> 4 waves/SIMD. waves=(nt,role): role0 =
//   offset+deform+epilogue (2 acc chains), role1 = conv5 (2 chains);
//   one end exchange. XCD y-swizzle: contiguous 8-row band per XCD.

#define EPSv 1e-5f
#define XP 68  // padded x stride: cols -2..65

typedef __attribute__((ext_vector_type(8))) short bf16x8;
typedef __attribute__((ext_vector_type(16))) float f32x16;
typedef __attribute__((ext_vector_type(2))) float f32x2;

__device__ inline ushort f2bf(float f) {
  __hip_bfloat16 h = __float2bfloat16(f);
  return *(ushort*)&h;
}
__device__ inline float bitsf(unsigned int u) {
  union { unsigned int i; float f; } c; c.i = u; return c.f;
}

// ---------------- prep: transpose x -> padded xTp + fragment-major weights ----------------
__global__ __launch_bounds__(256) void prep_kernel(
    const float* __restrict__ x, const float* __restrict__ w3,
    const float* __restrict__ w2, const float* __restrict__ w1,
    const float* __restrict__ w_off,
    ushort* __restrict__ xTp, ushort* __restrict__ w3F,
    ushort* __restrict__ w2F, ushort* __restrict__ w1F,
    ushort* __restrict__ wofF) {
  __shared__ float tile[64][65];
  const int blk = blockIdx.x;
  if (blk < 1024) {
    const int y = blk & 63, b = blk >> 6;
    for (int i = threadIdx.x; i < 4096; i += 256) {
      int ci = i >> 6, xx = i & 63;
      tile[ci][xx] = x[(((size_t)b * 64 + ci) * 64 + y) * 64 + xx];
    }
    __syncthreads();
    for (int i = threadIdx.x; i < 2048; i += 256) {
      int xx = i >> 5, cip = (i & 31) * 2;
      ushort2 v;
      v.x = f2bf(tile[cip][xx]);
      v.y = f2bf(tile[cip + 1][xx]);
      *(ushort2*)&xTp[(((size_t)(b * 64 + y) * XP) + (xx + 2)) * 64 + cip] = v;
    }
    // zero halo cols {0,1,66,67}
    if (threadIdx.x < 128) {
      int colid = threadIdx.x >> 5;
      int col = (colid & 1) + (colid >> 1) * 66;  // 0,1,66,67
      int cip = (threadIdx.x & 31) * 2;
      ushort2 z; z.x = 0; z.y = 0;
      *(ushort2*)&xTp[(((size_t)(b * 64 + y) * XP) + col) * 64 + cip] = z;
    }
    return;
  }
  int idx = (blk - 1024) * 256 + threadIdx.x;
  if (idx < 102400) {  // w3F
    int j = idx & 7, lane = (idx >> 3) & 63, ks = (idx >> 9) & 3;
    int half = (idx >> 11) & 1, kk = idx >> 12;
    int ln = lane & 31, kh = lane >> 5;
    int co = half * 32 + ln, ci = ks * 16 + kh * 8 + j;
    w3F[idx] = f2bf(w3[(co * 64 + ci) * 25 + kk]);
    return;
  }
  idx -= 102400;
  if (idx < 36864) {  // w2F
    int j = idx & 7, lane = (idx >> 3) & 63, ks = (idx >> 9) & 3;
    int half = (idx >> 11) & 1, kk = idx >> 12;
    int ln = lane & 31, kh = lane >> 5;
    int co = half * 32 + ln, ci = ks * 16 + kh * 8 + j;
    w2F[idx] = f2bf(w2[(co * 64 + ci) * 9 + kk]);
    return;
  }
  idx -= 36864;
  if (idx < 36864) {  // w1F
    int j = idx & 7, lane = (idx >> 3) & 63, ks = (idx >> 9) & 3;
    int half = (idx >> 11) & 1, kk = idx >> 12;
    int ln = lane & 31, kh = lane >> 5;
    int co = half * 32 + ln, ci = ks * 16 + kh * 8 + j;
    w1F[idx] = f2bf(w1[(co * 64 + ci) * 9 + kk]);
    return;
  }
  idx -= 36864;
  if (idx < 18432) {  // wofF
    int j = idx & 7, lane = (idx >> 3) & 63, ks = (idx >> 9) & 3;
    int kk = idx >> 11;
    int ln = lane & 31, kh = lane >> 5;
    int ci = ks * 16 + kh * 8 + j;
    wofF[idx] = f2bf(ln < 18 ? w_off[(ln * 64 + ci) * 9 + kk] : 0.f);
  }
}

// packed bilinear blend of 4 corner bf16x8 frags -> bf16x8
__device__ __forceinline__ bf16x8 blend4(bf16x8 va, bf16x8 vb, bf16x8 vc, bf16x8 vd,
                                         f32x2 w00v, f32x2 w01v, f32x2 w10v, f32x2 w11v) {
  const unsigned int* ua = (const unsigned int*)&va;
  const unsigned int* ub = (const unsigned int*)&vb;
  const unsigned int* uc = (const unsigned int*)&vc;
  const unsigned int* ud = (const unsigned int*)&vd;
  bf16x8 f;
  ushort2* fo = (ushort2*)&f;
#pragma unroll
  for (int d = 0; d < 4; ++d) {
    f32x2 av = {bitsf(ua[d] << 16), bitsf(ua[d] & 0xFFFF0000u)};
    f32x2 bv = {bitsf(ub[d] << 16), bitsf(ub[d] & 0xFFFF0000u)};
    f32x2 cv = {bitsf(uc[d] << 16), bitsf(uc[d] & 0xFFFF0000u)};
    f32x2 dv = {bitsf(ud[d] << 16), bitsf(ud[d] & 0xFFFF0000u)};
    f32x2 r = w00v * av + w01v * bv + w10v * cv + w11v * dv;
    __hip_bfloat162 h2 = __float22bfloat162_rn(make_float2(r.x, r.y));
    fo[d] = *(ushort2*)&h2;
  }
  return f;
}

// ---------------- fused: offset conv + deform + conv5 -> s1T (no x tile) ----------------
// Grid (64,16) 1-row blocks, 256 thr = 4 waves: nt = wv>>1 (px half),
// role = wv&1: 0 = offset+deform+epilogue, 1 = conv5. All B-frags from xTp.
__global__ __launch_bounds__(256, 4) void fused_kernel(
    const ushort* __restrict__ xTp, const ushort* __restrict__ wofF,
    const float* __restrict__ b_off, const ushort* __restrict__ w1F,
    const ushort* __restrict__ w3F,
    const float* __restrict__ g1, const float* __restrict__ b1,
    const float* __restrict__ m1, const float* __restrict__ v1,
    const float* __restrict__ g3, const float* __restrict__ b3,
    const float* __restrict__ m3, const float* __restrict__ v3,
    ushort* __restrict__ s1T) {
  __shared__ float stash[64 * 18];       // 4608 B offsets (same-wave RT)
  __shared__ float exch[2 * 64 * 32];    // 16384 B conv5 acc exchange
  __shared__ float bn1s[64], bn1b[64], bn3s[64], bn3b[64];  // 1024 B

  const int tid = threadIdx.x;
  const int wv = tid >> 6, lane = tid & 63;
  const int ln = lane & 31, kh = lane >> 5;
  const int role = wv & 1, nt = wv >> 1;
  const int yb = blockIdx.x, b = blockIdx.y;
  const int y = ((yb & 7) << 3) | (yb >> 3);  // XCD swizzle: contiguous 8-row band
  const int px = nt * 32 + ln;
  const ushort* xb = xTp + (size_t)b * 64 * XP * 64;

  if (tid < 64) {
    float s = g1[tid] * rsqrtf(v1[tid] + EPSv);
    bn1s[tid] = s; bn1b[tid] = b1[tid] - m1[tid] * s;
    float s3 = g3[tid] * rsqrtf(v3[tid] + EPSv);
    bn3s[tid] = s3; bn3b[tid] = b3[tid] - m3[tid] * s3;
  }
  __syncthreads();  // B1 (bn only)

  f32x16 accA, accB;
#pragma unroll
  for (int j = 0; j < 16; ++j) { accA[j] = 0.f; accB[j] = 0.f; }

  if (role == 0) {
    // ======== offset conv 3x3, full cin ========
    {
      f32x16 acco;
#pragma unroll
      for (int j = 0; j < 16; ++j) acco[j] = 0.f;
#pragma unroll
      for (int kk = 0; kk < 9; ++kk) {
        const int ky = kk / 3, kx = kk % 3;
        const int yy = y - 1 + ky;
        if (yy >= 0 && yy <= 63) {  // wave-uniform
          const ushort* rp = xb + ((size_t)(yy * XP + px + kx + 1)) * 64 + kh * 8;
#pragma unroll
          for (int ks = 0; ks < 4; ++ks) {
            bf16x8 af = *(const bf16x8*)&wofF[(size_t)((kk * 4 + ks) * 64 + lane) * 8];
            bf16x8 bf = *(const bf16x8*)(rp + ks * 16);
            acco = __builtin_amdgcn_mfma_f32_32x32x16_bf16(af, bf, acco, 0, 0, 0);
          }
        }
      }
#pragma unroll
      for (int reg = 0; reg < 16; ++reg) {
        int co = (reg & 3) + 8 * (reg >> 2) + 4 * kh;
        if (co < 18)
          stash[px * 18 + co] = acco[reg] + b_off[co];
      }
    }
    // same-wave LDS round-trip (in-order DS pipe; lanes ln/ln+32 exchange)
    asm volatile("" ::: "memory");
    float dyv[9], dxv[9];
#pragma unroll
    for (int kk = 0; kk < 9; ++kk) {
      dyv[kk] = stash[px * 18 + 2 * kk];
      dxv[kk] = stash[px * 18 + 2 * kk + 1];
    }

    // ======== deformable conv 3x3, full cin, single path ========
#pragma unroll
    for (int kk = 0; kk < 9; ++kk) {
      const int ky = kk / 3, kx = kk % 3;
      float ys = (float)(y - 1 + ky) + dyv[kk];
      float xs = (float)(px - 1 + kx) + dxv[kk];
      float y0f = floorf(ys), x0f = floorf(xs);
      float wy1 = ys - y0f, wx1 = xs - x0f;
      float wy0 = 1.f - wy1, wx0 = 1.f - wx1;
      int iy0 = (int)y0f, ix0 = (int)x0f;
      int iy1 = iy0 + 1, ix1 = ix0 + 1;
      float vy0 = (iy0 >= 0 && iy0 <= 63) ? 1.f : 0.f;
      float vy1 = (iy1 >= 0 && iy1 <= 63) ? 1.f : 0.f;
      float vx0 = (ix0 >= 0 && ix0 <= 63) ? 1.f : 0.f;
      float vx1 = (ix1 >= 0 && ix1 <= 63) ? 1.f : 0.f;
      int x0c = min(max(ix0, 0), 63), x1c = min(max(ix1, 0), 63);
      int y0c = min(max(iy0, 0), 63), y1c = min(max(iy1, 0), 63);
      float w00 = wy0 * wx0 * vy0 * vx0;
      float w01 = wy0 * wx1 * vy0 * vx1;
      float w10 = wy1 * wx0 * vy1 * vx0;
      float w11 = wy1 * wx1 * vy1 * vx1;
      f32x2 w00v = {w00, w00}, w01v = {w01, w01};
      f32x2 w10v = {w10, w10}, w11v = {w11, w11};
      const ushort* p00 = xb + ((size_t)(y0c * XP + x0c + 2)) * 64 + kh * 8;
      const ushort* p01 = xb + ((size_t)(y0c * XP + x1c + 2)) * 64 + kh * 8;
      const ushort* p10 = xb + ((size_t)(y1c * XP + x0c + 2)) * 64 + kh * 8;
      const ushort* p11 = xb + ((size_t)(y1c * XP + x1c + 2)) * 64 + kh * 8;
#pragma unroll
      for (int ks = 0; ks < 4; ++ks) {
        bf16x8 va = *(const bf16x8*)(p00 + ks * 16);
        bf16x8 vb = *(const bf16x8*)(p01 + ks * 16);
        bf16x8 vc = *(const bf16x8*)(p10 + ks * 16);
        bf16x8 vd = *(const bf16x8*)(p11 + ks * 16);
        bf16x8 f = blend4(va, vb, vc, vd, w00v, w01v, w10v, w11v);
        bf16x8 a0 = *(const bf16x8*)&w1F[(size_t)(((kk * 2 + 0) * 4 + ks) * 64 + lane) * 8];
        bf16x8 a1 = *(const bf16x8*)&w1F[(size_t)(((kk * 2 + 1) * 4 + ks) * 64 + lane) * 8];
        accA = __builtin_amdgcn_mfma_f32_32x32x16_bf16(a0, f, accA, 0, 0, 0);
        accB = __builtin_amdgcn_mfma_f32_32x32x16_bf16(a1, f, accB, 0, 0, 0);
      }
    }
  } else {
    // ======== conv 5x5, full cin ========
#pragma unroll
    for (int kk = 0; kk < 25; ++kk) {
      const int ky = kk / 5, kx = kk % 5;
      const int yy = y - 2 + ky;
      if (yy >= 0 && yy <= 63) {  // wave-uniform
        const ushort* rp = xb + ((size_t)(yy * XP + px + kx)) * 64 + kh * 8;
#pragma unroll
        for (int ks = 0; ks < 4; ++ks) {
          bf16x8 bf = *(const bf16x8*)(rp + ks * 16);
          bf16x8 a0 = *(const bf16x8*)&w3F[(size_t)(((kk * 2 + 0) * 4 + ks) * 64 + lane) * 8];
          bf16x8 a1 = *(const bf16x8*)&w3F[(size_t)(((kk * 2 + 1) * 4 + ks) * 64 + lane) * 8];
          accA = __builtin_amdgcn_mfma_f32_32x32x16_bf16(a0, bf, accA, 0, 0, 0);
          accB = __builtin_amdgcn_mfma_f32_32x32x16_bf16(a1, bf, accB, 0, 0, 0);
        }
      }
    }
  }

  // ---------- exchange: conv5 accs -> role0 waves ----------
  __syncthreads();  // B2
  float4* sp = (float4*)&exch[(size_t)(nt * 64 + lane) * 32];
  const int sw = lane & 7;
  if (role) {
    union { f32x16 v; float4 q[4]; } ua, ub;
    ua.v = accA; ub.v = accB;
    sp[0 ^ sw] = ua.q[0]; sp[1 ^ sw] = ua.q[1];
    sp[2 ^ sw] = ua.q[2]; sp[3 ^ sw] = ua.q[3];
    sp[4 ^ sw] = ub.q[0]; sp[5 ^ sw] = ub.q[1];
    sp[6 ^ sw] = ub.q[2]; sp[7 ^ sw] = ub.q[3];
  }
  __syncthreads();  // B3
  if (!role) {
    union { f32x16 v; float4 q[4]; } ua, ub;
    ua.q[0] = sp[0 ^ sw]; ua.q[1] = sp[1 ^ sw];
    ua.q[2] = sp[2 ^ sw]; ua.q[3] = sp[3 ^ sw];
    ub.q[0] = sp[4 ^ sw]; ub.q[1] = sp[5 ^ sw];
    ub.q[2] = sp[6 ^ sw]; ub.q[3] = sp[7 ^ sw];

    // ---------- epilogue (role0 waves only) ----------
    ushort* op = s1T + ((size_t)((b * 64 + y) * 64 + px)) * 64;
#pragma unroll
    for (int q = 0; q < 4; ++q) {
      int co0 = 8 * q + 4 * kh;
      float vv[4];
#pragma unroll
      for (int rr = 0; rr < 4; ++rr) {
        int co = co0 + rr;
        float vd = accA[q * 4 + rr] * bn1s[co] + bn1b[co];
        vd = vd > 0.f ? vd : 0.f;
        float v5 = ua.v[q * 4 + rr] * bn3s[co] + bn3b[co];
        v5 = v5 > 0.f ? v5 : 0.f;
        vv[rr] = vd + v5;
      }
      ushort4 st;
      st.x = f2bf(vv[0]); st.y = f2bf(vv[1]); st.z = f2bf(vv[2]); st.w = f2bf(vv[3]);
      *(ushort4*)(op + co0) = st;
#pragma unroll
      for (int rr = 0; rr < 4; ++rr) {
        int co = co0 + 32 + rr;
        float vd = accB[q * 4 + rr] * bn1s[co] + bn1b[co];
        vd = vd > 0.f ? vd : 0.f;
        float v5 = ub.v[q * 4 + rr] * bn3s[co] + bn3b[co];
        v5 = v5 > 0.f ? v5 : 0.f;
        vv[rr] = vd + v5;
      }
      st.x = f2bf(vv[0]); st.y = f2bf(vv[1]); st.z = f2bf(vv[2]); st.w = f2bf(vv[3]);
      *(ushort4*)(op + co0 + 32) = st;
    }
  }
}

// ---------------- conv3x3 on s1T + BN2 + residual + ReLU -> out ----------------
// 1-row blocks. Grid (64,16)=1024 blocks, 256 thr = 4 waves (mh, nt).
__global__ __launch_bounds__(256, 2) void conv3_mfma_kernel(
    const ushort* __restrict__ s1T, const ushort* __restrict__ w2F,
    const float* __restrict__ g2, const float* __restrict__ b2,
    const float* __restrict__ m2, const float* __restrict__ v2,
    const float* __restrict__ x, float* __restrict__ out) {
  __shared__ __align__(16) uint4 Bt[3 * 66 * 8];  // 25344 B swizzled
  __shared__ float sc[64], bi[64];
  const int tid = threadIdx.x;
  if (tid < 64) {
    float s = g2[tid] * rsqrtf(v2[tid] + EPSv);
    sc[tid] = s;
    bi[tid] = b2[tid] - m2[tid] * s;
  }
  const int y = blockIdx.x, b = blockIdx.y;
  const int wv = tid >> 6, lane = tid & 63;
  const int ln = lane & 31, kh = lane >> 5;
  const int mh = wv & 1, nt = wv >> 1;
  const int px = nt * 32 + ln;
  const uint4* s1T4 = (const uint4*)s1T;

  for (int i = tid; i < 3 * 66 * 8; i += 256) {
    int tr = i / (66 * 8), rem = i % (66 * 8);
    int col = rem >> 3, c = rem & 7;
    int yy = y - 1 + tr, xcol = col - 1;
    uint4 v = make_uint4(0, 0, 0, 0);
    if (yy >= 0 && yy <= 63 && xcol >= 0 && xcol <= 63)
      v = s1T4[((size_t)((b * 64 + yy) * 64 + xcol)) * 8 + c];
    Bt[(tr * 66 + col) * 8 + (c ^ (col & 7))] = v;
  }
  __syncthreads();

  f32x16 acc;
#pragma unroll
  for (int j = 0; j < 16; ++j) acc[j] = 0.f;

#pragma unroll
  for (int kk = 0; kk < 9; ++kk) {
    const int ky = kk / 3, kx = kk % 3;
    const int col = px + kx;
    bf16x8 af[4], bfr[4];
#pragma unroll
    for (int ccb = 0; ccb < 4; ++ccb)
      af[ccb] = *(const bf16x8*)&w2F[(size_t)(((kk * 2 + mh) * 4 + ccb) * 64 + lane) * 8];
#pragma unroll
    for (int ccb = 0; ccb < 4; ++ccb) {
      int c = ccb * 2 + kh;
      bfr[ccb] = *(const bf16x8*)&Bt[(ky * 66 + col) * 8 + (c ^ (col & 7))];
    }
#pragma unroll
    for (int ccb = 0; ccb < 4; ++ccb)
      acc = __builtin_amdgcn_mfma_f32_32x32x16_bf16(af[ccb], bfr[ccb], acc, 0, 0, 0);
  }
#pragma unroll
  for (int reg = 0; reg < 16; ++reg) {
    int co = (reg & 3) + 8 * (reg >> 2) + 4 * kh + mh * 32;
    size_t o = (((size_t)b * 64 + co) * 64 + y) * 64 + px;
    float v = acc[reg] * sc[co] + bi[co] + x[o];
    out[o] = v > 0.f ? v : 0.f;
  }
}

extern "C" void kernel_launch(void* const* d_in, const int* in_sizes, int n_in,
                              void* d_out, int out_size, void* d_ws, size_t ws_size,
                              hipStream_t stream) {
  const float* x     = (const float*)d_in[0];
  const float* w_off = (const float*)d_in[1];
  const float* b_off = (const float*)d_in[2];
  const float* w1    = (const float*)d_in[3];
  const float* g1    = (const float*)d_in[4];
  const float* b1    = (const float*)d_in[5];
  const float* m1    = (const float*)d_in[6];
  const float* v1    = (const float*)d_in[7];
  const float* w3    = (const float*)d_in[8];
  const float* g3    = (const float*)d_in[9];
  const float* b3    = (const float*)d_in[10];
  const float* m3    = (const float*)d_in[11];
  const float* v3    = (const float*)d_in[12];
  const float* w2    = (const float*)d_in[13];
  const float* g2    = (const float*)d_in[14];
  const float* b2    = (const float*)d_in[15];
  const float* m2    = (const float*)d_in[16];
  const float* v2    = (const float*)d_in[17];
  float* out = (float*)d_out;

  ushort* xTp  = (ushort*)d_ws;                        // 16*64*68*64 = 8.9 MB
  ushort* s1T  = xTp + (size_t)16 * 64 * XP * 64;      // 8.39 MB
  ushort* w3F  = s1T + (size_t)16 * 64 * 64 * 64;      // 102400
  ushort* w2F  = w3F + 102400;                         // 36864
  ushort* w1F  = w2F + 36864;                          // 36864
  ushort* wofF = w1F + 36864;                          // 18432

  prep_kernel<<<dim3(1024 + 760), dim3(256), 0, stream>>>(x, w3, w2, w1, w_off,
                                                          xTp, w3F, w2F, w1F, wofF);
  fused_kernel<<<dim3(64, 16), dim3(256), 0, stream>>>(xTp, wofF, b_off, w1F, w3F,
                                                       g1, b1, m1, v1, g3, b3, m3, v3,
                                                       s1T);
  conv3_mfma_kernel<<<dim3(64, 16), dim3(256), 0, stream>>>(s1T, w2F, g2, b2, m2, v2,
                                                            x, out);
}

// Round 5
// 86.475 us; speedup vs baseline: 1.2315x; 1.2315x over previous
//
#include <hip/hip_runtime.h>
#include <hip/hip_bf16.h>

// BasicBlock9: B=16, CIN=CP=64, H=W=64, K1=3 (deform), K2=5, EPS=1e-5
// R19: R14 skeleton (best measured 50us: 2-row blocks, 4 self-contained
//   waves, 2 blocks/CU) + hybrid operand routing:
//   - offset conv + conv5 B-frags read DIRECTLY from halo-padded xTp
//     (regular streaming pattern, L1/L2 friendly) -> per-block LDS reads
//     1120 -> 576 (-49%), cutting the dominant LDS-pipe time (41K cyc/CU
//     in R14: 27K reads + 14K conflicts).
//   - deform keeps the LDS tile (scattered corner gathers NEED LDS: R18
//     proved moving them to VMEM thrashes L1 -> 91us).
//   - offset conv has no tile dependency -> runs UNDER the tile staging
//     (ds_writes issue first, barrier after offset conv). B2 stash
//     barrier replaced by same-wave fence (validated R17/R18).
//   - padded xTp makes tile staging bound-check-free.

#define EPSv 1e-5f
#define XP 68  // padded x stride: cols -2..65

typedef __attribute__((ext_vector_type(8))) short bf16x8;
typedef __attribute__((ext_vector_type(16))) float f32x16;
typedef __attribute__((ext_vector_type(2))) float f32x2;

__device__ inline ushort f2bf(float f) {
  __hip_bfloat16 h = __float2bfloat16(f);
  return *(ushort*)&h;
}
__device__ inline float bitsf(unsigned int u) {
  union { unsigned int i; float f; } c; c.i = u; return c.f;
}

// ---------------- prep: transpose x -> padded xTp + fragment-major weights ----------------
__global__ __launch_bounds__(256) void prep_kernel(
    const float* __restrict__ x, const float* __restrict__ w3,
    const float* __restrict__ w2, const float* __restrict__ w1,
    const float* __restrict__ w_off,
    ushort* __restrict__ xTp, ushort* __restrict__ w3F,
    ushort* __restrict__ w2F, ushort* __restrict__ w1F,
    ushort* __restrict__ wofF) {
  __shared__ float tile[64][65];
  const int blk = blockIdx.x;
  if (blk < 1024) {
    const int y = blk & 63, b = blk >> 6;
    for (int i = threadIdx.x; i < 4096; i += 256) {
      int ci = i >> 6, xx = i & 63;
      tile[ci][xx] = x[(((size_t)b * 64 + ci) * 64 + y) * 64 + xx];
    }
    __syncthreads();
    for (int i = threadIdx.x; i < 2048; i += 256) {
      int xx = i >> 5, cip = (i & 31) * 2;
      ushort2 v;
      v.x = f2bf(tile[cip][xx]);
      v.y = f2bf(tile[cip + 1][xx]);
      *(ushort2*)&xTp[(((size_t)(b * 64 + y) * XP) + (xx + 2)) * 64 + cip] = v;
    }
    // zero halo cols {0,1,66,67}
    if (threadIdx.x < 128) {
      int colid = threadIdx.x >> 5;
      int col = (colid & 1) + (colid >> 1) * 66;  // 0,1,66,67
      int cip = (threadIdx.x & 31) * 2;
      ushort2 z; z.x = 0; z.y = 0;
      *(ushort2*)&xTp[(((size_t)(b * 64 + y) * XP) + col) * 64 + cip] = z;
    }
    return;
  }
  int idx = (blk - 1024) * 256 + threadIdx.x;
  if (idx < 102400) {  // w3F
    int j = idx & 7, lane = (idx >> 3) & 63, ks = (idx >> 9) & 3;
    int half = (idx >> 11) & 1, kk = idx >> 12;
    int ln = lane & 31, kh = lane >> 5;
    int co = half * 32 + ln, ci = ks * 16 + kh * 8 + j;
    w3F[idx] = f2bf(w3[(co * 64 + ci) * 25 + kk]);
    return;
  }
  idx -= 102400;
  if (idx < 36864) {  // w2F
    int j = idx & 7, lane = (idx >> 3) & 63, ks = (idx >> 9) & 3;
    int half = (idx >> 11) & 1, kk = idx >> 12;
    int ln = lane & 31, kh = lane >> 5;
    int co = half * 32 + ln, ci = ks * 16 + kh * 8 + j;
    w2F[idx] = f2bf(w2[(co * 64 + ci) * 9 + kk]);
    return;
  }
  idx -= 36864;
  if (idx < 36864) {  // w1F
    int j = idx & 7, lane = (idx >> 3) & 63, ks = (idx >> 9) & 3;
    int half = (idx >> 11) & 1, kk = idx >> 12;
    int ln = lane & 31, kh = lane >> 5;
    int co = half * 32 + ln, ci = ks * 16 + kh * 8 + j;
    w1F[idx] = f2bf(w1[(co * 64 + ci) * 9 + kk]);
    return;
  }
  idx -= 36864;
  if (idx < 18432) {  // wofF
    int j = idx & 7, lane = (idx >> 3) & 63, ks = (idx >> 9) & 3;
    int kk = idx >> 11;
    int ln = lane & 31, kh = lane >> 5;
    int ci = ks * 16 + kh * 8 + j;
    wofF[idx] = f2bf(ln < 18 ? w_off[(ln * 64 + ci) * 9 + kk] : 0.f);
  }
}

// packed bilinear blend of 4 corner bf16x8 frags -> bf16x8
__device__ __forceinline__ bf16x8 blend4(bf16x8 va, bf16x8 vb, bf16x8 vc, bf16x8 vd,
                                         f32x2 w00v, f32x2 w01v, f32x2 w10v, f32x2 w11v) {
  const unsigned int* ua = (const unsigned int*)&va;
  const unsigned int* ub = (const unsigned int*)&vb;
  const unsigned int* uc = (const unsigned int*)&vc;
  const unsigned int* ud = (const unsigned int*)&vd;
  bf16x8 f;
  ushort2* fo = (ushort2*)&f;
#pragma unroll
  for (int d = 0; d < 4; ++d) {
    f32x2 av = {bitsf(ua[d] << 16), bitsf(ua[d] & 0xFFFF0000u)};
    f32x2 bv = {bitsf(ub[d] << 16), bitsf(ub[d] & 0xFFFF0000u)};
    f32x2 cv = {bitsf(uc[d] << 16), bitsf(uc[d] & 0xFFFF0000u)};
    f32x2 dv = {bitsf(ud[d] << 16), bitsf(ud[d] & 0xFFFF0000u)};
    f32x2 r = w00v * av + w01v * bv + w10v * cv + w11v * dv;
    __hip_bfloat162 h2 = __float22bfloat162_rn(make_float2(r.x, r.y));
    fo[d] = *(ushort2*)&h2;
  }
  return f;
}

// ---------------- fused: offset conv + deform + conv5 -> s1T ----------------
// Grid (32, 16), 256 thr = 4 waves: r = wv>>1 (row), nt = wv&1 (px half).
// Tile serves ONLY deform; offset conv + conv5 stream from xTp global.
__global__ __launch_bounds__(256, 2) void fused_kernel(
    const ushort* __restrict__ xTp, const ushort* __restrict__ wofF,
    const float* __restrict__ b_off, const ushort* __restrict__ w1F,
    const ushort* __restrict__ w3F,
    const float* __restrict__ g1, const float* __restrict__ b1,
    const float* __restrict__ m1, const float* __restrict__ v1,
    const float* __restrict__ g3, const float* __restrict__ b3,
    const float* __restrict__ m3, const float* __restrict__ v3,
    ushort* __restrict__ s1T) {
  __shared__ __align__(16) uint4 ldsx[6 * 68 * 8];  // 52224 B swizzled tile
  __shared__ float stash[2 * 64 * 18];              // 9216 B offsets
  __shared__ float bn1s[64], bn1b[64], bn3s[64], bn3b[64];  // 1024 B

  const int tid = threadIdx.x;
  const int wv = tid >> 6, lane = tid & 63;
  const int ln = lane & 31, kh = lane >> 5;
  const int r = wv >> 1, nt = wv & 1;
  const int y0 = blockIdx.x * 2, b = blockIdx.y;
  const int y = y0 + r, px = nt * 32 + ln;
  const uint4* xT4 = (const uint4*)xTp;
  const ushort* xb = xTp + (size_t)b * 64 * XP * 64;

  if (tid < 64) {
    float s = g1[tid] * rsqrtf(v1[tid] + EPSv);
    bn1s[tid] = s; bn1b[tid] = b1[tid] - m1[tid] * s;
    float s3 = g3[tid] * rsqrtf(v3[tid] + EPSv);
    bn3s[tid] = s3; bn3b[tid] = b3[tid] - m3[tid] * s3;
  }
  // issue tile staging (rows y0-2..y0+3 clamped; padded cols -> no bounds check)
  for (int i = tid; i < 6 * 68 * 8; i += 256) {
    int tr = i / (68 * 8), rem = i % (68 * 8);
    int col = rem >> 3, c = rem & 7;
    int ysrc = min(max(y0 - 2 + tr, 0), 63);
    uint4 v = xT4[((size_t)((b * 64 + ysrc) * XP + col)) * 8 + c];
    ldsx[(tr * 68 + col) * 8 + (c ^ (col & 7))] = v;
  }

  // ---------- phase 1: offset conv 3x3 from GLOBAL (overlaps staging) ----------
  {
    f32x16 acco;
#pragma unroll
    for (int j = 0; j < 16; ++j) acco[j] = 0.f;
#pragma unroll
    for (int kk = 0; kk < 9; ++kk) {
      const int ky = kk / 3, kx = kk % 3;
      const int yy = y - 1 + ky;
      if (yy >= 0 && yy <= 63) {  // wave-uniform
        const ushort* rp = xb + ((size_t)(yy * XP + px + kx + 1)) * 64 + kh * 8;
#pragma unroll
        for (int ks = 0; ks < 4; ++ks) {
          bf16x8 af = *(const bf16x8*)&wofF[(size_t)((kk * 4 + ks) * 64 + lane) * 8];
          bf16x8 bf = *(const bf16x8*)(rp + ks * 16);
          acco = __builtin_amdgcn_mfma_f32_32x32x16_bf16(af, bf, acco, 0, 0, 0);
        }
      }
    }
#pragma unroll
    for (int reg = 0; reg < 16; ++reg) {
      int co = (reg & 3) + 8 * (reg >> 2) + 4 * kh;
      if (co < 18)
        stash[(r * 64 + px) * 18 + co] = acco[reg] + b_off[co];
    }
  }
  // same-wave LDS round-trip (in-order DS pipe; lanes ln/ln+32 exchange)
  asm volatile("" ::: "memory");
  float dyv[9], dxv[9];
#pragma unroll
  for (int kk = 0; kk < 9; ++kk) {
    dyv[kk] = stash[(r * 64 + px) * 18 + 2 * kk];
    dxv[kk] = stash[(r * 64 + px) * 18 + 2 * kk + 1];
  }
  bool fast = true;
#pragma unroll
  for (int kk = 0; kk < 9; ++kk) {
    int iy0 = (int)floorf((float)(y - 1 + kk / 3) + dyv[kk]);
    int iy1 = iy0 + 1;
    bool ok0 = (iy0 < 0) || (iy0 > 63) || (iy0 >= y0 - 2 && iy0 <= y0 + 3);
    bool ok1 = (iy1 < 0) || (iy1 > 63) || (iy1 >= y0 - 2 && iy1 <= y0 + 3);
    fast = fast && ok0 && ok1;
  }
  __syncthreads();  // B1: tile staged (only barrier)

  // ---------- phase 2: deformable conv 3x3 (tile fast path / global mixed) ----------
  f32x16 accd0, accd1;
#pragma unroll
  for (int j = 0; j < 16; ++j) { accd0[j] = 0.f; accd1[j] = 0.f; }

  if (__ballot(!fast) == 0ull) {
    // -------- branch-free fast loop (whole wave in-tile) --------
#pragma unroll
    for (int kk = 0; kk < 9; ++kk) {
      const int ky = kk / 3, kx = kk % 3;
      float ys = (float)(y - 1 + ky) + dyv[kk];
      float xs = (float)(px - 1 + kx) + dxv[kk];
      float y0f = floorf(ys), x0f = floorf(xs);
      float wy1 = ys - y0f, wx1 = xs - x0f;
      float wy0 = 1.f - wy1, wx0 = 1.f - wx1;
      int iy0 = (int)y0f, ix0 = (int)x0f;
      int iy1 = iy0 + 1, ix1 = ix0 + 1;
      float vy0 = (iy0 >= 0 && iy0 <= 63) ? 1.f : 0.f;
      float vy1 = (iy1 >= 0 && iy1 <= 63) ? 1.f : 0.f;
      float vx0 = (ix0 >= 0 && ix0 <= 63) ? 1.f : 0.f;
      float vx1 = (ix1 >= 0 && ix1 <= 63) ? 1.f : 0.f;
      int x0c = min(max(ix0, 0), 63), x1c = min(max(ix1, 0), 63);
      float w00 = wy0 * wx0 * vy0 * vx0;
      float w01 = wy0 * wx1 * vy0 * vx1;
      float w10 = wy1 * wx0 * vy1 * vx0;
      float w11 = wy1 * wx1 * vy1 * vx1;
      int tr0 = min(max(iy0 - (y0 - 2), 0), 5);
      int tr1 = min(max(iy1 - (y0 - 2), 0), 5);
      int c0 = x0c + 2, c1 = x1c + 2;
      f32x2 w00v = {w00, w00}, w01v = {w01, w01};
      f32x2 w10v = {w10, w10}, w11v = {w11, w11};

      bf16x8 a0[4], a1[4], va[4], vb[4], vc[4], vd[4];
#pragma unroll
      for (int ks = 0; ks < 4; ++ks) {
        a0[ks] = *(const bf16x8*)&w1F[(size_t)(((kk * 2 + 0) * 4 + ks) * 64 + lane) * 8];
        a1[ks] = *(const bf16x8*)&w1F[(size_t)(((kk * 2 + 1) * 4 + ks) * 64 + lane) * 8];
      }
#pragma unroll
      for (int ks = 0; ks < 4; ++ks) {
        int c = ks * 2 + kh;
        va[ks] = *(const bf16x8*)&ldsx[(tr0 * 68 + c0) * 8 + (c ^ (c0 & 7))];
        vb[ks] = *(const bf16x8*)&ldsx[(tr0 * 68 + c1) * 8 + (c ^ (c1 & 7))];
        vc[ks] = *(const bf16x8*)&ldsx[(tr1 * 68 + c0) * 8 + (c ^ (c0 & 7))];
        vd[ks] = *(const bf16x8*)&ldsx[(tr1 * 68 + c1) * 8 + (c ^ (c1 & 7))];
      }
#pragma unroll
      for (int ks = 0; ks < 4; ++ks) {
        bf16x8 f = blend4(va[ks], vb[ks], vc[ks], vd[ks], w00v, w01v, w10v, w11v);
        accd0 = __builtin_amdgcn_mfma_f32_32x32x16_bf16(a0[ks], f, accd0, 0, 0, 0);
        accd1 = __builtin_amdgcn_mfma_f32_32x32x16_bf16(a1[ks], f, accd1, 0, 0, 0);
      }
    }
  } else {
    // -------- mixed loop (rare: some lane needs global gather) --------
#pragma unroll
    for (int kk = 0; kk < 9; ++kk) {
      const int ky = kk / 3, kx = kk % 3;
      float ys = (float)(y - 1 + ky) + dyv[kk];
      float xs = (float)(px - 1 + kx) + dxv[kk];
      float y0f = floorf(ys), x0f = floorf(xs);
      float wy1 = ys - y0f, wx1 = xs - x0f;
      float wy0 = 1.f - wy1, wx0 = 1.f - wx1;
      int iy0 = (int)y0f, ix0 = (int)x0f;
      int iy1 = iy0 + 1, ix1 = ix0 + 1;
      float vy0 = (iy0 >= 0 && iy0 <= 63) ? 1.f : 0.f;
      float vy1 = (iy1 >= 0 && iy1 <= 63) ? 1.f : 0.f;
      float vx0 = (ix0 >= 0 && ix0 <= 63) ? 1.f : 0.f;
      float vx1 = (ix1 >= 0 && ix1 <= 63) ? 1.f : 0.f;
      int x0c = min(max(ix0, 0), 63), x1c = min(max(ix1, 0), 63);
      int y0c = min(max(iy0, 0), 63), y1c = min(max(iy1, 0), 63);
      float w00 = wy0 * wx0 * vy0 * vx0;
      float w01 = wy0 * wx1 * vy0 * vx1;
      float w10 = wy1 * wx0 * vy1 * vx0;
      float w11 = wy1 * wx1 * vy1 * vx1;
      f32x2 w00v = {w00, w00}, w01v = {w01, w01};
      f32x2 w10v = {w10, w10}, w11v = {w11, w11};
      const ushort* p00 = xb + ((size_t)(y0c * XP + x0c + 2)) * 64 + kh * 8;
      const ushort* p01 = xb + ((size_t)(y0c * XP + x1c + 2)) * 64 + kh * 8;
      const ushort* p10 = xb + ((size_t)(y1c * XP + x0c + 2)) * 64 + kh * 8;
      const ushort* p11 = xb + ((size_t)(y1c * XP + x1c + 2)) * 64 + kh * 8;
#pragma unroll
      for (int ks = 0; ks < 4; ++ks) {
        bf16x8 va = *(const bf16x8*)(p00 + ks * 16);
        bf16x8 vb = *(const bf16x8*)(p01 + ks * 16);
        bf16x8 vc = *(const bf16x8*)(p10 + ks * 16);
        bf16x8 vd = *(const bf16x8*)(p11 + ks * 16);
        bf16x8 f = blend4(va, vb, vc, vd, w00v, w01v, w10v, w11v);
        bf16x8 a0 = *(const bf16x8*)&w1F[(size_t)(((kk * 2 + 0) * 4 + ks) * 64 + lane) * 8];
        bf16x8 a1 = *(const bf16x8*)&w1F[(size_t)(((kk * 2 + 1) * 4 + ks) * 64 + lane) * 8];
        accd0 = __builtin_amdgcn_mfma_f32_32x32x16_bf16(a0, f, accd0, 0, 0, 0);
        accd1 = __builtin_amdgcn_mfma_f32_32x32x16_bf16(a1, f, accd1, 0, 0, 0);
      }
    }
  }

  // ---------- phase 3: conv 5x5 from GLOBAL ----------
  f32x16 acc50, acc51;
#pragma unroll
  for (int j = 0; j < 16; ++j) { acc50[j] = 0.f; acc51[j] = 0.f; }
#pragma unroll
  for (int kk = 0; kk < 25; ++kk) {
    const int ky = kk / 5, kx = kk % 5;
    const int yy = y - 2 + ky;
    if (yy >= 0 && yy <= 63) {  // wave-uniform
      const ushort* rp = xb + ((size_t)(yy * XP + px + kx)) * 64 + kh * 8;
#pragma unroll
      for (int ks = 0; ks < 4; ++ks) {
        bf16x8 bf = *(const bf16x8*)(rp + ks * 16);
        bf16x8 a0 = *(const bf16x8*)&w3F[(size_t)(((kk * 2 + 0) * 4 + ks) * 64 + lane) * 8];
        bf16x8 a1 = *(const bf16x8*)&w3F[(size_t)(((kk * 2 + 1) * 4 + ks) * 64 + lane) * 8];
        acc50 = __builtin_amdgcn_mfma_f32_32x32x16_bf16(a0, bf, acc50, 0, 0, 0);
        acc51 = __builtin_amdgcn_mfma_f32_32x32x16_bf16(a1, bf, acc51, 0, 0, 0);
      }
    }
  }

  // ---------- epilogue ----------
  ushort* op = s1T + ((size_t)((b * 64 + y) * 64 + px)) * 64;
#pragma unroll
  for (int q = 0; q < 4; ++q) {
    int co0 = 8 * q + 4 * kh;
    float vv[4];
#pragma unroll
    for (int rr = 0; rr < 4; ++rr) {
      int co = co0 + rr;
      float vd = accd0[q * 4 + rr] * bn1s[co] + bn1b[co];
      vd = vd > 0.f ? vd : 0.f;
      float v5 = acc50[q * 4 + rr] * bn3s[co] + bn3b[co];
      v5 = v5 > 0.f ? v5 : 0.f;
      vv[rr] = vd + v5;
    }
    ushort4 st;
    st.x = f2bf(vv[0]); st.y = f2bf(vv[1]); st.z = f2bf(vv[2]); st.w = f2bf(vv[3]);
    *(ushort4*)(op + co0) = st;
#pragma unroll
    for (int rr = 0; rr < 4; ++rr) {
      int co = co0 + 32 + rr;
      float vd = accd1[q * 4 + rr] * bn1s[co] + bn1b[co];
      vd = vd > 0.f ? vd : 0.f;
      float v5 = acc51[q * 4 + rr] * bn3s[co] + bn3b[co];
      v5 = v5 > 0.f ? v5 : 0.f;
      vv[rr] = vd + v5;
    }
    st.x = f2bf(vv[0]); st.y = f2bf(vv[1]); st.z = f2bf(vv[2]); st.w = f2bf(vv[3]);
    *(ushort4*)(op + co0 + 32) = st;
  }
}

// ---------------- conv3x3 on s1T + BN2 + residual + ReLU -> out ----------------
// 1-row blocks. Grid (64,16)=1024 blocks, 256 thr = 4 waves (mh, nt).
__global__ __launch_bounds__(256, 2) void conv3_mfma_kernel(
    const ushort* __restrict__ s1T, const ushort* __restrict__ w2F,
    const float* __restrict__ g2, const float* __restrict__ b2,
    const float* __restrict__ m2, const float* __restrict__ v2,
    const float* __restrict__ x, float* __restrict__ out) {
  __shared__ __align__(16) uint4 Bt[3 * 66 * 8];  // 25344 B swizzled
  __shared__ float sc[64], bi[64];
  const int tid = threadIdx.x;
  if (tid < 64) {
    float s = g2[tid] * rsqrtf(v2[tid] + EPSv);
    sc[tid] = s;
    bi[tid] = b2[tid] - m2[tid] * s;
  }
  const int y = blockIdx.x, b = blockIdx.y;
  const int wv = tid >> 6, lane = tid & 63;
  const int ln = lane & 31, kh = lane >> 5;
  const int mh = wv & 1, nt = wv >> 1;
  const int px = nt * 32 + ln;
  const uint4* s1T4 = (const uint4*)s1T;

  for (int i = tid; i < 3 * 66 * 8; i += 256) {
    int tr = i / (66 * 8), rem = i % (66 * 8);
    int col = rem >> 3, c = rem & 7;
    int yy = y - 1 + tr, xcol = col - 1;
    uint4 v = make_uint4(0, 0, 0, 0);
    if (yy >= 0 && yy <= 63 && xcol >= 0 && xcol <= 63)
      v = s1T4[((size_t)((b * 64 + yy) * 64 + xcol)) * 8 + c];
    Bt[(tr * 66 + col) * 8 + (c ^ (col & 7))] = v;
  }
  __syncthreads();

  f32x16 acc;
#pragma unroll
  for (int j = 0; j < 16; ++j) acc[j] = 0.f;

#pragma unroll
  for (int kk = 0; kk < 9; ++kk) {
    const int ky = kk / 3, kx = kk % 3;
    const int col = px + kx;
    bf16x8 af[4], bfr[4];
#pragma unroll
    for (int ccb = 0; ccb < 4; ++ccb)
      af[ccb] = *(const bf16x8*)&w2F[(size_t)(((kk * 2 + mh) * 4 + ccb) * 64 + lane) * 8];
#pragma unroll
    for (int ccb = 0; ccb < 4; ++ccb) {
      int c = ccb * 2 + kh;
      bfr[ccb] = *(const bf16x8*)&Bt[(ky * 66 + col) * 8 + (c ^ (col & 7))];
    }
#pragma unroll
    for (int ccb = 0; ccb < 4; ++ccb)
      acc = __builtin_amdgcn_mfma_f32_32x32x16_bf16(af[ccb], bfr[ccb], acc, 0, 0, 0);
  }
#pragma unroll
  for (int reg = 0; reg < 16; ++reg) {
    int co = (reg & 3) + 8 * (reg >> 2) + 4 * kh + mh * 32;
    size_t o = (((size_t)b * 64 + co) * 64 + y) * 64 + px;
    float v = acc[reg] * sc[co] + bi[co] + x[o];
    out[o] = v > 0.f ? v : 0.f;
  }
}

extern "C" void kernel_launch(void* const* d_in, const int* in_sizes, int n_in,
                              void* d_out, int out_size, void* d_ws, size_t ws_size,
                              hipStream_t stream) {
  const float* x     = (const float*)d_in[0];
  const float* w_off = (const float*)d_in[1];
  const float* b_off = (const float*)d_in[2];
  const float* w1    = (const float*)d_in[3];
  const float* g1    = (const float*)d_in[4];
  const float* b1    = (const float*)d_in[5];
  const float* m1    = (const float*)d_in[6];
  const float* v1    = (const float*)d_in[7];
  const float* w3    = (const float*)d_in[8];
  const float* g3    = (const float*)d_in[9];
  const float* b3    = (const float*)d_in[10];
  const float* m3    = (const float*)d_in[11];
  const float* v3    = (const float*)d_in[12];
  const float* w2    = (const float*)d_in[13];
  const float* g2    = (const float*)d_in[14];
  const float* b2    = (const float*)d_in[15];
  const float* m2    = (const float*)d_in[16];
  const float* v2    = (const float*)d_in[17];
  float* out = (float*)d_out;

  ushort* xTp  = (ushort*)d_ws;                        // 16*64*68*64 = 8.9 MB
  ushort* s1T  = xTp + (size_t)16 * 64 * XP * 64;      // 8.39 MB
  ushort* w3F  = s1T + (size_t)16 * 64 * 64 * 64;      // 102400
  ushort* w2F  = w3F + 102400;                         // 36864
  ushort* w1F  = w2F + 36864;                          // 36864
  ushort* wofF = w1F + 36864;                          // 18432

  prep_kernel<<<dim3(1024 + 760), dim3(256), 0, stream>>>(x, w3, w2, w1, w_off,
                                                          xTp, w3F, w2F, w1F, wofF);
  fused_kernel<<<dim3(32, 16), dim3(256), 0, stream>>>(xTp, wofF, b_off, w1F, w3F,
                                                       g1, b1, m1, v1, g3, b3, m3, v3,
                                                       s1T);
  conv3_mfma_kernel<<<dim3(64, 16), dim3(256), 0, stream>>>(s1T, w2F, g2, b2, m2, v2,
                                                            x, out);
}

// Round 6
// 73.926 us; speedup vs baseline: 1.4406x; 1.1698x over previous
//
#include <hip/hip_runtime.h>
#include <hip/hip_bf16.h>

// BasicBlock9: B=16, CIN=CP=64, H=W=64, K1=3 (deform), K2=5, EPS=1e-5
// R20: R14 skeleton (best measured: fused 50us) + minimal surgical delta:
//   (1) offset conv B-frags from halo-padded xTp GLOBAL, issued UNDER the
//       tile-staging ds_writes (independent vmcnt/lgkmcnt; no tile dep)
//   (2) stash barrier -> same-wave DS fence (validated R17-R19)
//   (3) staging bounds-check-free via padded xTp
//   => ONE barrier: {stage || offset(global)} -> B1 -> deform -> conv5.
//   Deform + conv5 keep R14's LDS paths verbatim (R18/R19 proved moving
//   them to VMEM at 2 waves/SIMD loses 20-40us to latency).

#define EPSv 1e-5f
#define XP 68  // padded x stride: cols -2..65

typedef __attribute__((ext_vector_type(8))) short bf16x8;
typedef __attribute__((ext_vector_type(16))) float f32x16;
typedef __attribute__((ext_vector_type(2))) float f32x2;

__device__ inline ushort f2bf(float f) {
  __hip_bfloat16 h = __float2bfloat16(f);
  return *(ushort*)&h;
}
__device__ inline float bitsf(unsigned int u) {
  union { unsigned int i; float f; } c; c.i = u; return c.f;
}

// ---------------- prep: transpose x -> padded xTp + fragment-major weights ----------------
__global__ __launch_bounds__(256) void prep_kernel(
    const float* __restrict__ x, const float* __restrict__ w3,
    const float* __restrict__ w2, const float* __restrict__ w1,
    const float* __restrict__ w_off,
    ushort* __restrict__ xTp, ushort* __restrict__ w3F,
    ushort* __restrict__ w2F, ushort* __restrict__ w1F,
    ushort* __restrict__ wofF) {
  __shared__ float tile[64][65];
  const int blk = blockIdx.x;
  if (blk < 1024) {
    const int y = blk & 63, b = blk >> 6;
    for (int i = threadIdx.x; i < 4096; i += 256) {
      int ci = i >> 6, xx = i & 63;
      tile[ci][xx] = x[(((size_t)b * 64 + ci) * 64 + y) * 64 + xx];
    }
    __syncthreads();
    for (int i = threadIdx.x; i < 2048; i += 256) {
      int xx = i >> 5, cip = (i & 31) * 2;
      ushort2 v;
      v.x = f2bf(tile[cip][xx]);
      v.y = f2bf(tile[cip + 1][xx]);
      *(ushort2*)&xTp[(((size_t)(b * 64 + y) * XP) + (xx + 2)) * 64 + cip] = v;
    }
    // zero halo cols {0,1,66,67}
    if (threadIdx.x < 128) {
      int colid = threadIdx.x >> 5;
      int col = (colid & 1) + (colid >> 1) * 66;  // 0,1,66,67
      int cip = (threadIdx.x & 31) * 2;
      ushort2 z; z.x = 0; z.y = 0;
      *(ushort2*)&xTp[(((size_t)(b * 64 + y) * XP) + col) * 64 + cip] = z;
    }
    return;
  }
  int idx = (blk - 1024) * 256 + threadIdx.x;
  if (idx < 102400) {  // w3F
    int j = idx & 7, lane = (idx >> 3) & 63, ks = (idx >> 9) & 3;
    int half = (idx >> 11) & 1, kk = idx >> 12;
    int ln = lane & 31, kh = lane >> 5;
    int co = half * 32 + ln, ci = ks * 16 + kh * 8 + j;
    w3F[idx] = f2bf(w3[(co * 64 + ci) * 25 + kk]);
    return;
  }
  idx -= 102400;
  if (idx < 36864) {  // w2F
    int j = idx & 7, lane = (idx >> 3) & 63, ks = (idx >> 9) & 3;
    int half = (idx >> 11) & 1, kk = idx >> 12;
    int ln = lane & 31, kh = lane >> 5;
    int co = half * 32 + ln, ci = ks * 16 + kh * 8 + j;
    w2F[idx] = f2bf(w2[(co * 64 + ci) * 9 + kk]);
    return;
  }
  idx -= 36864;
  if (idx < 36864) {  // w1F
    int j = idx & 7, lane = (idx >> 3) & 63, ks = (idx >> 9) & 3;
    int half = (idx >> 11) & 1, kk = idx >> 12;
    int ln = lane & 31, kh = lane >> 5;
    int co = half * 32 + ln, ci = ks * 16 + kh * 8 + j;
    w1F[idx] = f2bf(w1[(co * 64 + ci) * 9 + kk]);
    return;
  }
  idx -= 36864;
  if (idx < 18432) {  // wofF
    int j = idx & 7, lane = (idx >> 3) & 63, ks = (idx >> 9) & 3;
    int kk = idx >> 11;
    int ln = lane & 31, kh = lane >> 5;
    int ci = ks * 16 + kh * 8 + j;
    wofF[idx] = f2bf(ln < 18 ? w_off[(ln * 64 + ci) * 9 + kk] : 0.f);
  }
}

// packed bilinear blend of 4 corner bf16x8 frags -> bf16x8
__device__ __forceinline__ bf16x8 blend4(bf16x8 va, bf16x8 vb, bf16x8 vc, bf16x8 vd,
                                         f32x2 w00v, f32x2 w01v, f32x2 w10v, f32x2 w11v) {
  const unsigned int* ua = (const unsigned int*)&va;
  const unsigned int* ub = (const unsigned int*)&vb;
  const unsigned int* uc = (const unsigned int*)&vc;
  const unsigned int* ud = (const unsigned int*)&vd;
  bf16x8 f;
  ushort2* fo = (ushort2*)&f;
#pragma unroll
  for (int d = 0; d < 4; ++d) {
    f32x2 av = {bitsf(ua[d] << 16), bitsf(ua[d] & 0xFFFF0000u)};
    f32x2 bv = {bitsf(ub[d] << 16), bitsf(ub[d] & 0xFFFF0000u)};
    f32x2 cv = {bitsf(uc[d] << 16), bitsf(uc[d] & 0xFFFF0000u)};
    f32x2 dv = {bitsf(ud[d] << 16), bitsf(ud[d] & 0xFFFF0000u)};
    f32x2 r = w00v * av + w01v * bv + w10v * cv + w11v * dv;
    __hip_bfloat162 h2 = __float22bfloat162_rn(make_float2(r.x, r.y));
    fo[d] = *(ushort2*)&h2;
  }
  return f;
}

// ---------------- fused: offset conv + deform + conv5 -> s1T ----------------
// Grid (32, 16), 256 thr = 4 waves: r = wv>>1 (row), nt = wv&1 (px half).
__global__ __launch_bounds__(256, 2) void fused_kernel(
    const ushort* __restrict__ xTp, const ushort* __restrict__ wofF,
    const float* __restrict__ b_off, const ushort* __restrict__ w1F,
    const ushort* __restrict__ w3F,
    const float* __restrict__ g1, const float* __restrict__ b1,
    const float* __restrict__ m1, const float* __restrict__ v1,
    const float* __restrict__ g3, const float* __restrict__ b3,
    const float* __restrict__ m3, const float* __restrict__ v3,
    ushort* __restrict__ s1T) {
  __shared__ __align__(16) uint4 ldsx[6 * 68 * 8];  // 52224 B swizzled tile
  __shared__ float stash[2 * 64 * 18];              // 9216 B offsets
  __shared__ float bn1s[64], bn1b[64], bn3s[64], bn3b[64];  // 1024 B

  const int tid = threadIdx.x;
  const int wv = tid >> 6, lane = tid & 63;
  const int ln = lane & 31, kh = lane >> 5;
  const int r = wv >> 1, nt = wv & 1;
  const int y0 = blockIdx.x * 2, b = blockIdx.y;
  const int y = y0 + r, px = nt * 32 + ln;
  const uint4* xT4 = (const uint4*)xTp;
  const ushort* xb = xTp + (size_t)b * 64 * XP * 64;
  const bool interior = (y0 >= 2 && y0 <= 60);  // block-uniform

  if (tid < 64) {
    float s = g1[tid] * rsqrtf(v1[tid] + EPSv);
    bn1s[tid] = s; bn1b[tid] = b1[tid] - m1[tid] * s;
    float s3 = g3[tid] * rsqrtf(v3[tid] + EPSv);
    bn3s[tid] = s3; bn3b[tid] = b3[tid] - m3[tid] * s3;
  }
  // issue tile staging (rows y0-2..y0+3 clamped; padded cols, no bounds check)
  for (int i = tid; i < 6 * 68 * 8; i += 256) {
    int tr = i / (68 * 8), rem = i % (68 * 8);
    int col = rem >> 3, c = rem & 7;
    int ysrc = min(max(y0 - 2 + tr, 0), 63);
    uint4 v = xT4[((size_t)((b * 64 + ysrc) * XP + col)) * 8 + c];
    ldsx[(tr * 68 + col) * 8 + (c ^ (col & 7))] = v;
  }

  // ---------- phase 1: offset conv 3x3 from GLOBAL (overlaps staging) ----------
  {
    f32x16 acco;
#pragma unroll
    for (int j = 0; j < 16; ++j) acco[j] = 0.f;
#pragma unroll
    for (int kk = 0; kk < 9; ++kk) {
      const int ky = kk / 3, kx = kk % 3;
      const int yy = y - 1 + ky;
      if (yy >= 0 && yy <= 63) {  // wave-uniform
        const ushort* rp = xb + ((size_t)(yy * XP + px + kx + 1)) * 64 + kh * 8;
#pragma unroll
        for (int ks = 0; ks < 4; ++ks) {
          bf16x8 af = *(const bf16x8*)&wofF[(size_t)((kk * 4 + ks) * 64 + lane) * 8];
          bf16x8 bf = *(const bf16x8*)(rp + ks * 16);
          acco = __builtin_amdgcn_mfma_f32_32x32x16_bf16(af, bf, acco, 0, 0, 0);
        }
      }
    }
#pragma unroll
    for (int reg = 0; reg < 16; ++reg) {
      int co = (reg & 3) + 8 * (reg >> 2) + 4 * kh;
      if (co < 18)
        stash[(r * 64 + px) * 18 + co] = acco[reg] + b_off[co];
    }
  }
  // same-wave LDS round-trip (in-order DS pipe; lanes ln/ln+32 exchange)
  asm volatile("" ::: "memory");
  float dyv[9], dxv[9];
#pragma unroll
  for (int kk = 0; kk < 9; ++kk) {
    dyv[kk] = stash[(r * 64 + px) * 18 + 2 * kk];
    dxv[kk] = stash[(r * 64 + px) * 18 + 2 * kk + 1];
  }
  bool fast = true;
#pragma unroll
  for (int kk = 0; kk < 9; ++kk) {
    int iy0 = (int)floorf((float)(y - 1 + kk / 3) + dyv[kk]);
    int iy1 = iy0 + 1;
    bool ok0 = (iy0 < 0) || (iy0 > 63) || (iy0 >= y0 - 2 && iy0 <= y0 + 3);
    bool ok1 = (iy1 < 0) || (iy1 > 63) || (iy1 >= y0 - 2 && iy1 <= y0 + 3);
    fast = fast && ok0 && ok1;
  }
  __syncthreads();  // B1: tile staged (only barrier)

  // ---------- phase 2: deformable conv 3x3 ----------
  f32x16 accd0, accd1;
#pragma unroll
  for (int j = 0; j < 16; ++j) { accd0[j] = 0.f; accd1[j] = 0.f; }

  if (__ballot(!fast) == 0ull) {
    // -------- branch-free fast loop (whole wave in-tile) --------
#pragma unroll
    for (int kk = 0; kk < 9; ++kk) {
      const int ky = kk / 3, kx = kk % 3;
      float ys = (float)(y - 1 + ky) + dyv[kk];
      float xs = (float)(px - 1 + kx) + dxv[kk];
      float y0f = floorf(ys), x0f = floorf(xs);
      float wy1 = ys - y0f, wx1 = xs - x0f;
      float wy0 = 1.f - wy1, wx0 = 1.f - wx1;
      int iy0 = (int)y0f, ix0 = (int)x0f;
      int iy1 = iy0 + 1, ix1 = ix0 + 1;
      float vy0 = (iy0 >= 0 && iy0 <= 63) ? 1.f : 0.f;
      float vy1 = (iy1 >= 0 && iy1 <= 63) ? 1.f : 0.f;
      float vx0 = (ix0 >= 0 && ix0 <= 63) ? 1.f : 0.f;
      float vx1 = (ix1 >= 0 && ix1 <= 63) ? 1.f : 0.f;
      int x0c = min(max(ix0, 0), 63), x1c = min(max(ix1, 0), 63);
      float w00 = wy0 * wx0 * vy0 * vx0;
      float w01 = wy0 * wx1 * vy0 * vx1;
      float w10 = wy1 * wx0 * vy1 * vx0;
      float w11 = wy1 * wx1 * vy1 * vx1;
      int tr0 = min(max(iy0 - (y0 - 2), 0), 5);
      int tr1 = min(max(iy1 - (y0 - 2), 0), 5);
      int c0 = x0c + 2, c1 = x1c + 2;
      f32x2 w00v = {w00, w00}, w01v = {w01, w01};
      f32x2 w10v = {w10, w10}, w11v = {w11, w11};

      bf16x8 a0[4], a1[4], va[4], vb[4], vc[4], vd[4];
#pragma unroll
      for (int ks = 0; ks < 4; ++ks) {
        a0[ks] = *(const bf16x8*)&w1F[(size_t)(((kk * 2 + 0) * 4 + ks) * 64 + lane) * 8];
        a1[ks] = *(const bf16x8*)&w1F[(size_t)(((kk * 2 + 1) * 4 + ks) * 64 + lane) * 8];
      }
#pragma unroll
      for (int ks = 0; ks < 4; ++ks) {
        int c = ks * 2 + kh;
        va[ks] = *(const bf16x8*)&ldsx[(tr0 * 68 + c0) * 8 + (c ^ (c0 & 7))];
        vb[ks] = *(const bf16x8*)&ldsx[(tr0 * 68 + c1) * 8 + (c ^ (c1 & 7))];
        vc[ks] = *(const bf16x8*)&ldsx[(tr1 * 68 + c0) * 8 + (c ^ (c0 & 7))];
        vd[ks] = *(const bf16x8*)&ldsx[(tr1 * 68 + c1) * 8 + (c ^ (c1 & 7))];
      }
#pragma unroll
      for (int ks = 0; ks < 4; ++ks) {
        bf16x8 f = blend4(va[ks], vb[ks], vc[ks], vd[ks], w00v, w01v, w10v, w11v);
        accd0 = __builtin_amdgcn_mfma_f32_32x32x16_bf16(a0[ks], f, accd0, 0, 0, 0);
        accd1 = __builtin_amdgcn_mfma_f32_32x32x16_bf16(a1[ks], f, accd1, 0, 0, 0);
      }
    }
  } else {
    // -------- mixed loop (rare: some lane needs global gather) --------
#pragma unroll
    for (int kk = 0; kk < 9; ++kk) {
      const int ky = kk / 3, kx = kk % 3;
      float ys = (float)(y - 1 + ky) + dyv[kk];
      float xs = (float)(px - 1 + kx) + dxv[kk];
      float y0f = floorf(ys), x0f = floorf(xs);
      float wy1 = ys - y0f, wx1 = xs - x0f;
      float wy0 = 1.f - wy1, wx0 = 1.f - wx1;
      int iy0 = (int)y0f, ix0 = (int)x0f;
      int iy1 = iy0 + 1, ix1 = ix0 + 1;
      float vy0 = (iy0 >= 0 && iy0 <= 63) ? 1.f : 0.f;
      float vy1 = (iy1 >= 0 && iy1 <= 63) ? 1.f : 0.f;
      float vx0 = (ix0 >= 0 && ix0 <= 63) ? 1.f : 0.f;
      float vx1 = (ix1 >= 0 && ix1 <= 63) ? 1.f : 0.f;
      int x0c = min(max(ix0, 0), 63), x1c = min(max(ix1, 0), 63);
      int y0c = min(max(iy0, 0), 63), y1c = min(max(iy1, 0), 63);
      float w00 = wy0 * wx0 * vy0 * vx0;
      float w01 = wy0 * wx1 * vy0 * vx1;
      float w10 = wy1 * wx0 * vy1 * vx0;
      float w11 = wy1 * wx1 * vy1 * vx1;
      int tr0 = min(max(iy0 - (y0 - 2), 0), 5);
      int tr1 = min(max(iy1 - (y0 - 2), 0), 5);
      int c0 = x0c + 2, c1 = x1c + 2;
      f32x2 w00v = {w00, w00}, w01v = {w01, w01};
      f32x2 w10v = {w10, w10}, w11v = {w11, w11};

      bf16x8 frag[4];
#pragma unroll
      for (int ks = 0; ks < 4; ++ks) {
        int c = ks * 2 + kh;
        bf16x8 va = *(const bf16x8*)&ldsx[(tr0 * 68 + c0) * 8 + (c ^ (c0 & 7))];
        bf16x8 vb = *(const bf16x8*)&ldsx[(tr0 * 68 + c1) * 8 + (c ^ (c1 & 7))];
        bf16x8 vc = *(const bf16x8*)&ldsx[(tr1 * 68 + c0) * 8 + (c ^ (c0 & 7))];
        bf16x8 vd = *(const bf16x8*)&ldsx[(tr1 * 68 + c1) * 8 + (c ^ (c1 & 7))];
        frag[ks] = blend4(va, vb, vc, vd, w00v, w01v, w10v, w11v);
      }
      if (!fast) {
        const ushort* p00 = xb + ((size_t)(y0c * XP + x0c + 2)) * 64 + kh * 8;
        const ushort* p01 = xb + ((size_t)(y0c * XP + x1c + 2)) * 64 + kh * 8;
        const ushort* p10 = xb + ((size_t)(y1c * XP + x0c + 2)) * 64 + kh * 8;
        const ushort* p11 = xb + ((size_t)(y1c * XP + x1c + 2)) * 64 + kh * 8;
#pragma unroll
        for (int ks = 0; ks < 4; ++ks) {
          bf16x8 va = *(const bf16x8*)(p00 + ks * 16);
          bf16x8 vb = *(const bf16x8*)(p01 + ks * 16);
          bf16x8 vc = *(const bf16x8*)(p10 + ks * 16);
          bf16x8 vd = *(const bf16x8*)(p11 + ks * 16);
          frag[ks] = blend4(va, vb, vc, vd, w00v, w01v, w10v, w11v);
        }
      }
#pragma unroll
      for (int ks = 0; ks < 4; ++ks) {
        bf16x8 a0 = *(const bf16x8*)&w1F[(size_t)(((kk * 2 + 0) * 4 + ks) * 64 + lane) * 8];
        bf16x8 a1 = *(const bf16x8*)&w1F[(size_t)(((kk * 2 + 1) * 4 + ks) * 64 + lane) * 8];
        accd0 = __builtin_amdgcn_mfma_f32_32x32x16_bf16(a0, frag[ks], accd0, 0, 0, 0);
        accd1 = __builtin_amdgcn_mfma_f32_32x32x16_bf16(a1, frag[ks], accd1, 0, 0, 0);
      }
    }
  }

  // ---------- phase 3: conv 5x5 from LDS (R14 verbatim) ----------
  f32x16 acc50, acc51;
#pragma unroll
  for (int j = 0; j < 16; ++j) { acc50[j] = 0.f; acc51[j] = 0.f; }
  if (interior) {
#pragma unroll
    for (int kk = 0; kk < 25; ++kk) {
      const int ky = kk / 5, kx = kk % 5;
      const int tr = r + ky;
      const int col = px + kx;
      bf16x8 a0[4], a1[4], bfv[4];
#pragma unroll
      for (int ks = 0; ks < 4; ++ks) {
        a0[ks] = *(const bf16x8*)&w3F[(size_t)(((kk * 2 + 0) * 4 + ks) * 64 + lane) * 8];
        a1[ks] = *(const bf16x8*)&w3F[(size_t)(((kk * 2 + 1) * 4 + ks) * 64 + lane) * 8];
      }
#pragma unroll
      for (int ks = 0; ks < 4; ++ks) {
        int c = ks * 2 + kh;
        bfv[ks] = *(const bf16x8*)&ldsx[(tr * 68 + col) * 8 + (c ^ (col & 7))];
      }
#pragma unroll
      for (int ks = 0; ks < 4; ++ks) {
        acc50 = __builtin_amdgcn_mfma_f32_32x32x16_bf16(a0[ks], bfv[ks], acc50, 0, 0, 0);
        acc51 = __builtin_amdgcn_mfma_f32_32x32x16_bf16(a1[ks], bfv[ks], acc51, 0, 0, 0);
      }
    }
  } else {
#pragma unroll
    for (int kk = 0; kk < 25; ++kk) {
      const int ky = kk / 5, kx = kk % 5;
      const int yy = y - 2 + ky;
      if (yy >= 0 && yy <= 63) {  // wave-uniform
        const int tr = r + ky;
        const int col = px + kx;
#pragma unroll
        for (int ks = 0; ks < 4; ++ks) {
          int c = ks * 2 + kh;
          bf16x8 bf = *(const bf16x8*)&ldsx[(tr * 68 + col) * 8 + (c ^ (col & 7))];
          bf16x8 a0 = *(const bf16x8*)&w3F[(size_t)(((kk * 2 + 0) * 4 + ks) * 64 + lane) * 8];
          bf16x8 a1 = *(const bf16x8*)&w3F[(size_t)(((kk * 2 + 1) * 4 + ks) * 64 + lane) * 8];
          acc50 = __builtin_amdgcn_mfma_f32_32x32x16_bf16(a0, bf, acc50, 0, 0, 0);
          acc51 = __builtin_amdgcn_mfma_f32_32x32x16_bf16(a1, bf, acc51, 0, 0, 0);
        }
      }
    }
  }

  // ---------- epilogue ----------
  ushort* op = s1T + ((size_t)((b * 64 + y) * 64 + px)) * 64;
#pragma unroll
  for (int q = 0; q < 4; ++q) {
    int co0 = 8 * q + 4 * kh;
    float vv[4];
#pragma unroll
    for (int rr = 0; rr < 4; ++rr) {
      int co = co0 + rr;
      float vd = accd0[q * 4 + rr] * bn1s[co] + bn1b[co];
      vd = vd > 0.f ? vd : 0.f;
      float v5 = acc50[q * 4 + rr] * bn3s[co] + bn3b[co];
      v5 = v5 > 0.f ? v5 : 0.f;
      vv[rr] = vd + v5;
    }
    ushort4 st;
    st.x = f2bf(vv[0]); st.y = f2bf(vv[1]); st.z = f2bf(vv[2]); st.w = f2bf(vv[3]);
    *(ushort4*)(op + co0) = st;
#pragma unroll
    for (int rr = 0; rr < 4; ++rr) {
      int co = co0 + 32 + rr;
      float vd = accd1[q * 4 + rr] * bn1s[co] + bn1b[co];
      vd = vd > 0.f ? vd : 0.f;
      float v5 = acc51[q * 4 + rr] * bn3s[co] + bn3b[co];
      v5 = v5 > 0.f ? v5 : 0.f;
      vv[rr] = vd + v5;
    }
    st.x = f2bf(vv[0]); st.y = f2bf(vv[1]); st.z = f2bf(vv[2]); st.w = f2bf(vv[3]);
    *(ushort4*)(op + co0 + 32) = st;
  }
}

// ---------------- conv3x3 on s1T + BN2 + residual + ReLU -> out ----------------
// 1-row blocks. Grid (64,16)=1024 blocks, 256 thr = 4 waves (mh, nt).
__global__ __launch_bounds__(256, 2) void conv3_mfma_kernel(
    const ushort* __restrict__ s1T, const ushort* __restrict__ w2F,
    const float* __restrict__ g2, const float* __restrict__ b2,
    const float* __restrict__ m2, const float* __restrict__ v2,
    const float* __restrict__ x, float* __restrict__ out) {
  __shared__ __align__(16) uint4 Bt[3 * 66 * 8];  // 25344 B swizzled
  __shared__ float sc[64], bi[64];
  const int tid = threadIdx.x;
  if (tid < 64) {
    float s = g2[tid] * rsqrtf(v2[tid] + EPSv);
    sc[tid] = s;
    bi[tid] = b2[tid] - m2[tid] * s;
  }
  const int y = blockIdx.x, b = blockIdx.y;
  const int wv = tid >> 6, lane = tid & 63;
  const int ln = lane & 31, kh = lane >> 5;
  const int mh = wv & 1, nt = wv >> 1;
  const int px = nt * 32 + ln;
  const uint4* s1T4 = (const uint4*)s1T;

  for (int i = tid; i < 3 * 66 * 8; i += 256) {
    int tr = i / (66 * 8), rem = i % (66 * 8);
    int col = rem >> 3, c = rem & 7;
    int yy = y - 1 + tr, xcol = col - 1;
    uint4 v = make_uint4(0, 0, 0, 0);
    if (yy >= 0 && yy <= 63 && xcol >= 0 && xcol <= 63)
      v = s1T4[((size_t)((b * 64 + yy) * 64 + xcol)) * 8 + c];
    Bt[(tr * 66 + col) * 8 + (c ^ (col & 7))] = v;
  }
  __syncthreads();

  f32x16 acc;
#pragma unroll
  for (int j = 0; j < 16; ++j) acc[j] = 0.f;

#pragma unroll
  for (int kk = 0; kk < 9; ++kk) {
    const int ky = kk / 3, kx = kk % 3;
    const int col = px + kx;
    bf16x8 af[4], bfr[4];
#pragma unroll
    for (int ccb = 0; ccb < 4; ++ccb)
      af[ccb] = *(const bf16x8*)&w2F[(size_t)(((kk * 2 + mh) * 4 + ccb) * 64 + lane) * 8];
#pragma unroll
    for (int ccb = 0; ccb < 4; ++ccb) {
      int c = ccb * 2 + kh;
      bfr[ccb] = *(const bf16x8*)&Bt[(ky * 66 + col) * 8 + (c ^ (col & 7))];
    }
#pragma unroll
    for (int ccb = 0; ccb < 4; ++ccb)
      acc = __builtin_amdgcn_mfma_f32_32x32x16_bf16(af[ccb], bfr[ccb], acc, 0, 0, 0);
  }
#pragma unroll
  for (int reg = 0; reg < 16; ++reg) {
    int co = (reg & 3) + 8 * (reg >> 2) + 4 * kh + mh * 32;
    size_t o = (((size_t)b * 64 + co) * 64 + y) * 64 + px;
    float v = acc[reg] * sc[co] + bi[co] + x[o];
    out[o] = v > 0.f ? v : 0.f;
  }
}

extern "C" void kernel_launch(void* const* d_in, const int* in_sizes, int n_in,
                              void* d_out, int out_size, void* d_ws, size_t ws_size,
                              hipStream_t stream) {
  const float* x     = (const float*)d_in[0];
  const float* w_off = (const float*)d_in[1];
  const float* b_off = (const float*)d_in[2];
  const float* w1    = (const float*)d_in[3];
  const float* g1    = (const float*)d_in[4];
  const float* b1    = (const float*)d_in[5];
  const float* m1    = (const float*)d_in[6];
  const float* v1    = (const float*)d_in[7];
  const float* w3    = (const float*)d_in[8];
  const float* g3    = (const float*)d_in[9];
  const float* b3    = (const float*)d_in[10];
  const float* m3    = (const float*)d_in[11];
  const float* v3    = (const float*)d_in[12];
  const float* w2    = (const float*)d_in[13];
  const float* g2    = (const float*)d_in[14];
  const float* b2    = (const float*)d_in[15];
  const float* m2    = (const float*)d_in[16];
  const float* v2    = (const float*)d_in[17];
  float* out = (float*)d_out;

  ushort* xTp  = (ushort*)d_ws;                        // 16*64*68*64 = 8.9 MB
  ushort* s1T  = xTp + (size_t)16 * 64 * XP * 64;      // 8.39 MB
  ushort* w3F  = s1T + (size_t)16 * 64 * 64 * 64;      // 102400
  ushort* w2F  = w3F + 102400;                         // 36864
  ushort* w1F  = w2F + 36864;                          // 36864
  ushort* wofF = w1F + 36864;                          // 18432

  prep_kernel<<<dim3(1024 + 760), dim3(256), 0, stream>>>(x, w3, w2, w1, w_off,
                                                          xTp, w3F, w2F, w1F, wofF);
  fused_kernel<<<dim3(32, 16), dim3(256), 0, stream>>>(xTp, wofF, b_off, w1F, w3F,
                                                       g1, b1, m1, v1, g3, b3, m3, v3,
                                                       s1T);
  conv3_mfma_kernel<<<dim3(64, 16), dim3(256), 0, stream>>>(s1T, w2F, g2, b2, m2, v2,
                                                            x, out);
}

// Round 7
// 68.018 us; speedup vs baseline: 1.5657x; 1.0869x over previous
//
#include <hip/hip_runtime.h>
#include <hip/hip_bf16.h>

// BasicBlock9: B=16, CIN=CP=64, H=W=64, K1=3 (deform), K2=5, EPS=1e-5
// R21: R14 restored (best measured: fused 50.2us, total 69.0us) + only the
//   deltas validated harmless/positive across R17-R20:
//   (1) padded-xTp staging loop: no bounds branch, fewer VALU (R20: conflicts
//       3.5M->3.25M with this staging)
//   (2) stash barrier B2 -> same-wave DS fence (correctness validated 4x):
//       ONE barrier total (B1 after staging)
//   (3) deform mixed-path global fallback reads via padded xTp
//   ALL compute routing identical to R14: offset conv from LDS, deform LDS
//   fast path, conv5 LDS. R15-R20 proved: VMEM routing of any B-operand at
//   2 waves/SIMD loses (R18 91us, R19 71us, R20 57us); more waves spills
//   (R15/R16) or multiplies staging (R17 88us).

#define EPSv 1e-5f
#define XP 68  // padded x stride: cols -2..65

typedef __attribute__((ext_vector_type(8))) short bf16x8;
typedef __attribute__((ext_vector_type(16))) float f32x16;
typedef __attribute__((ext_vector_type(2))) float f32x2;

__device__ inline ushort f2bf(float f) {
  __hip_bfloat16 h = __float2bfloat16(f);
  return *(ushort*)&h;
}
__device__ inline float bitsf(unsigned int u) {
  union { unsigned int i; float f; } c; c.i = u; return c.f;
}

// ---------------- prep: transpose x -> padded xTp + fragment-major weights ----------------
__global__ __launch_bounds__(256) void prep_kernel(
    const float* __restrict__ x, const float* __restrict__ w3,
    const float* __restrict__ w2, const float* __restrict__ w1,
    const float* __restrict__ w_off,
    ushort* __restrict__ xTp, ushort* __restrict__ w3F,
    ushort* __restrict__ w2F, ushort* __restrict__ w1F,
    ushort* __restrict__ wofF) {
  __shared__ float tile[64][65];
  const int blk = blockIdx.x;
  if (blk < 1024) {
    const int y = blk & 63, b = blk >> 6;
    for (int i = threadIdx.x; i < 4096; i += 256) {
      int ci = i >> 6, xx = i & 63;
      tile[ci][xx] = x[(((size_t)b * 64 + ci) * 64 + y) * 64 + xx];
    }
    __syncthreads();
    for (int i = threadIdx.x; i < 2048; i += 256) {
      int xx = i >> 5, cip = (i & 31) * 2;
      ushort2 v;
      v.x = f2bf(tile[cip][xx]);
      v.y = f2bf(tile[cip + 1][xx]);
      *(ushort2*)&xTp[(((size_t)(b * 64 + y) * XP) + (xx + 2)) * 64 + cip] = v;
    }
    // zero halo cols {0,1,66,67}
    if (threadIdx.x < 128) {
      int colid = threadIdx.x >> 5;
      int col = (colid & 1) + (colid >> 1) * 66;  // 0,1,66,67
      int cip = (threadIdx.x & 31) * 2;
      ushort2 z; z.x = 0; z.y = 0;
      *(ushort2*)&xTp[(((size_t)(b * 64 + y) * XP) + col) * 64 + cip] = z;
    }
    return;
  }
  int idx = (blk - 1024) * 256 + threadIdx.x;
  if (idx < 102400) {  // w3F
    int j = idx & 7, lane = (idx >> 3) & 63, ks = (idx >> 9) & 3;
    int half = (idx >> 11) & 1, kk = idx >> 12;
    int ln = lane & 31, kh = lane >> 5;
    int co = half * 32 + ln, ci = ks * 16 + kh * 8 + j;
    w3F[idx] = f2bf(w3[(co * 64 + ci) * 25 + kk]);
    return;
  }
  idx -= 102400;
  if (idx < 36864) {  // w2F
    int j = idx & 7, lane = (idx >> 3) & 63, ks = (idx >> 9) & 3;
    int half = (idx >> 11) & 1, kk = idx >> 12;
    int ln = lane & 31, kh = lane >> 5;
    int co = half * 32 + ln, ci = ks * 16 + kh * 8 + j;
    w2F[idx] = f2bf(w2[(co * 64 + ci) * 9 + kk]);
    return;
  }
  idx -= 36864;
  if (idx < 36864) {  // w1F
    int j = idx & 7, lane = (idx >> 3) & 63, ks = (idx >> 9) & 3;
    int half = (idx >> 11) & 1, kk = idx >> 12;
    int ln = lane & 31, kh = lane >> 5;
    int co = half * 32 + ln, ci = ks * 16 + kh * 8 + j;
    w1F[idx] = f2bf(w1[(co * 64 + ci) * 9 + kk]);
    return;
  }
  idx -= 36864;
  if (idx < 18432) {  // wofF
    int j = idx & 7, lane = (idx >> 3) & 63, ks = (idx >> 9) & 3;
    int kk = idx >> 11;
    int ln = lane & 31, kh = lane >> 5;
    int ci = ks * 16 + kh * 8 + j;
    wofF[idx] = f2bf(ln < 18 ? w_off[(ln * 64 + ci) * 9 + kk] : 0.f);
  }
}

// packed bilinear blend of 4 corner bf16x8 frags -> bf16x8
__device__ __forceinline__ bf16x8 blend4(bf16x8 va, bf16x8 vb, bf16x8 vc, bf16x8 vd,
                                         f32x2 w00v, f32x2 w01v, f32x2 w10v, f32x2 w11v) {
  const unsigned int* ua = (const unsigned int*)&va;
  const unsigned int* ub = (const unsigned int*)&vb;
  const unsigned int* uc = (const unsigned int*)&vc;
  const unsigned int* ud = (const unsigned int*)&vd;
  bf16x8 f;
  ushort2* fo = (ushort2*)&f;
#pragma unroll
  for (int d = 0; d < 4; ++d) {
    f32x2 av = {bitsf(ua[d] << 16), bitsf(ua[d] & 0xFFFF0000u)};
    f32x2 bv = {bitsf(ub[d] << 16), bitsf(ub[d] & 0xFFFF0000u)};
    f32x2 cv = {bitsf(uc[d] << 16), bitsf(uc[d] & 0xFFFF0000u)};
    f32x2 dv = {bitsf(ud[d] << 16), bitsf(ud[d] & 0xFFFF0000u)};
    f32x2 r = w00v * av + w01v * bv + w10v * cv + w11v * dv;
    __hip_bfloat162 h2 = __float22bfloat162_rn(make_float2(r.x, r.y));
    fo[d] = *(ushort2*)&h2;
  }
  return f;
}

// ---------------- fused: offset conv + deform + conv5 -> s1T (R14 routing) ----------------
// Grid (32, 16), 256 thr = 4 waves: r = wv>>1 (row), nt = wv&1 (px half).
__global__ __launch_bounds__(256, 2) void fused_kernel(
    const ushort* __restrict__ xTp, const ushort* __restrict__ wofF,
    const float* __restrict__ b_off, const ushort* __restrict__ w1F,
    const ushort* __restrict__ w3F,
    const float* __restrict__ g1, const float* __restrict__ b1,
    const float* __restrict__ m1, const float* __restrict__ v1,
    const float* __restrict__ g3, const float* __restrict__ b3,
    const float* __restrict__ m3, const float* __restrict__ v3,
    ushort* __restrict__ s1T) {
  __shared__ __align__(16) uint4 ldsx[6 * 68 * 8];  // 52224 B swizzled tile
  __shared__ float stash[2 * 64 * 18];              // 9216 B offsets
  __shared__ float bn1s[64], bn1b[64], bn3s[64], bn3b[64];  // 1024 B

  const int tid = threadIdx.x;
  const int wv = tid >> 6, lane = tid & 63;
  const int ln = lane & 31, kh = lane >> 5;
  const int r = wv >> 1, nt = wv & 1;
  const int y0 = blockIdx.x * 2, b = blockIdx.y;
  const int y = y0 + r, px = nt * 32 + ln;
  const uint4* xT4 = (const uint4*)xTp;
  const ushort* xb = xTp + (size_t)b * 64 * XP * 64;
  const bool interior = (y0 >= 2 && y0 <= 60);  // block-uniform

  if (tid < 64) {
    float s = g1[tid] * rsqrtf(v1[tid] + EPSv);
    bn1s[tid] = s; bn1b[tid] = b1[tid] - m1[tid] * s;
    float s3 = g3[tid] * rsqrtf(v3[tid] + EPSv);
    bn3s[tid] = s3; bn3b[tid] = b3[tid] - m3[tid] * s3;
  }
  // stage rows y0-2..y0+3 (clamped), all 68 padded cols: no bounds branch
  for (int i = tid; i < 6 * 68 * 8; i += 256) {
    int tr = i / (68 * 8), rem = i % (68 * 8);
    int col = rem >> 3, c = rem & 7;
    int ysrc = min(max(y0 - 2 + tr, 0), 63);
    uint4 v = xT4[((size_t)((b * 64 + ysrc) * XP + col)) * 8 + c];
    ldsx[(tr * 68 + col) * 8 + (c ^ (col & 7))] = v;
  }
  __syncthreads();  // B1: tile staged (only barrier in kernel)

  // ---------- phase 1: offset conv 3x3 from LDS (R14 verbatim) ----------
  f32x16 acco;
#pragma unroll
  for (int j = 0; j < 16; ++j) acco[j] = 0.f;
  if (interior) {
#pragma unroll
    for (int kk = 0; kk < 9; ++kk) {
      const int ky = kk / 3, kx = kk % 3;
      const int tr = r + ky + 1;
      const int col = px + kx + 1;
      bf16x8 af[4], bf[4];
#pragma unroll
      for (int ks = 0; ks < 4; ++ks)
        af[ks] = *(const bf16x8*)&wofF[(size_t)((kk * 4 + ks) * 64 + lane) * 8];
#pragma unroll
      for (int ks = 0; ks < 4; ++ks) {
        int c = ks * 2 + kh;
        bf[ks] = *(const bf16x8*)&ldsx[(tr * 68 + col) * 8 + (c ^ (col & 7))];
      }
#pragma unroll
      for (int ks = 0; ks < 4; ++ks)
        acco = __builtin_amdgcn_mfma_f32_32x32x16_bf16(af[ks], bf[ks], acco, 0, 0, 0);
    }
  } else {
#pragma unroll
    for (int kk = 0; kk < 9; ++kk) {
      const int ky = kk / 3, kx = kk % 3;
      const int yy = y - 1 + ky;
      if (yy >= 0 && yy <= 63) {  // wave-uniform
        const int tr = yy - (y0 - 2);
        const int col = px + kx + 1;
#pragma unroll
        for (int ks = 0; ks < 4; ++ks) {
          int c = ks * 2 + kh;
          bf16x8 af = *(const bf16x8*)&wofF[(size_t)((kk * 4 + ks) * 64 + lane) * 8];
          bf16x8 bf = *(const bf16x8*)&ldsx[(tr * 68 + col) * 8 + (c ^ (col & 7))];
          acco = __builtin_amdgcn_mfma_f32_32x32x16_bf16(af, bf, acco, 0, 0, 0);
        }
      }
    }
  }
#pragma unroll
  for (int reg = 0; reg < 16; ++reg) {
    int co = (reg & 3) + 8 * (reg >> 2) + 4 * kh;
    if (co < 18)
      stash[(r * 64 + px) * 18 + co] = acco[reg] + b_off[co];
  }
  // same-wave LDS round-trip: DS pipe in-order per wave; lanes ln/ln+32
  // of THIS wave wrote this px's 18 values. No barrier needed.
  asm volatile("" ::: "memory");

  float dyv[9], dxv[9];
#pragma unroll
  for (int kk = 0; kk < 9; ++kk) {
    dyv[kk] = stash[(r * 64 + px) * 18 + 2 * kk];
    dxv[kk] = stash[(r * 64 + px) * 18 + 2 * kk + 1];
  }
  bool fast = true;
#pragma unroll
  for (int kk = 0; kk < 9; ++kk) {
    int iy0 = (int)floorf((float)(y - 1 + kk / 3) + dyv[kk]);
    int iy1 = iy0 + 1;
    bool ok0 = (iy0 < 0) || (iy0 > 63) || (iy0 >= y0 - 2 && iy0 <= y0 + 3);
    bool ok1 = (iy1 < 0) || (iy1 > 63) || (iy1 >= y0 - 2 && iy1 <= y0 + 3);
    fast = fast && ok0 && ok1;
  }

  // ---------- phase 2: deformable conv 3x3 (R14 verbatim) ----------
  f32x16 accd0, accd1;
#pragma unroll
  for (int j = 0; j < 16; ++j) { accd0[j] = 0.f; accd1[j] = 0.f; }

  if (__ballot(!fast) == 0ull) {
    // -------- branch-free fast loop (whole wave in-tile) --------
#pragma unroll
    for (int kk = 0; kk < 9; ++kk) {
      const int ky = kk / 3, kx = kk % 3;
      float ys = (float)(y - 1 + ky) + dyv[kk];
      float xs = (float)(px - 1 + kx) + dxv[kk];
      float y0f = floorf(ys), x0f = floorf(xs);
      float wy1 = ys - y0f, wx1 = xs - x0f;
      float wy0 = 1.f - wy1, wx0 = 1.f - wx1;
      int iy0 = (int)y0f, ix0 = (int)x0f;
      int iy1 = iy0 + 1, ix1 = ix0 + 1;
      float vy0 = (iy0 >= 0 && iy0 <= 63) ? 1.f : 0.f;
      float vy1 = (iy1 >= 0 && iy1 <= 63) ? 1.f : 0.f;
      float vx0 = (ix0 >= 0 && ix0 <= 63) ? 1.f : 0.f;
      float vx1 = (ix1 >= 0 && ix1 <= 63) ? 1.f : 0.f;
      int x0c = min(max(ix0, 0), 63), x1c = min(max(ix1, 0), 63);
      float w00 = wy0 * wx0 * vy0 * vx0;
      float w01 = wy0 * wx1 * vy0 * vx1;
      float w10 = wy1 * wx0 * vy1 * vx0;
      float w11 = wy1 * wx1 * vy1 * vx1;
      int tr0 = min(max(iy0 - (y0 - 2), 0), 5);
      int tr1 = min(max(iy1 - (y0 - 2), 0), 5);
      int c0 = x0c + 2, c1 = x1c + 2;
      f32x2 w00v = {w00, w00}, w01v = {w01, w01};
      f32x2 w10v = {w10, w10}, w11v = {w11, w11};

      bf16x8 a0[4], a1[4], va[4], vb[4], vc[4], vd[4];
#pragma unroll
      for (int ks = 0; ks < 4; ++ks) {
        a0[ks] = *(const bf16x8*)&w1F[(size_t)(((kk * 2 + 0) * 4 + ks) * 64 + lane) * 8];
        a1[ks] = *(const bf16x8*)&w1F[(size_t)(((kk * 2 + 1) * 4 + ks) * 64 + lane) * 8];
      }
#pragma unroll
      for (int ks = 0; ks < 4; ++ks) {
        int c = ks * 2 + kh;
        va[ks] = *(const bf16x8*)&ldsx[(tr0 * 68 + c0) * 8 + (c ^ (c0 & 7))];
        vb[ks] = *(const bf16x8*)&ldsx[(tr0 * 68 + c1) * 8 + (c ^ (c1 & 7))];
        vc[ks] = *(const bf16x8*)&ldsx[(tr1 * 68 + c0) * 8 + (c ^ (c0 & 7))];
        vd[ks] = *(const bf16x8*)&ldsx[(tr1 * 68 + c1) * 8 + (c ^ (c1 & 7))];
      }
#pragma unroll
      for (int ks = 0; ks < 4; ++ks) {
        bf16x8 f = blend4(va[ks], vb[ks], vc[ks], vd[ks], w00v, w01v, w10v, w11v);
        accd0 = __builtin_amdgcn_mfma_f32_32x32x16_bf16(a0[ks], f, accd0, 0, 0, 0);
        accd1 = __builtin_amdgcn_mfma_f32_32x32x16_bf16(a1[ks], f, accd1, 0, 0, 0);
      }
    }
  } else {
    // -------- mixed loop (rare: some lane needs global gather) --------
#pragma unroll
    for (int kk = 0; kk < 9; ++kk) {
      const int ky = kk / 3, kx = kk % 3;
      float ys = (float)(y - 1 + ky) + dyv[kk];
      float xs = (float)(px - 1 + kx) + dxv[kk];
      float y0f = floorf(ys), x0f = floorf(xs);
      float wy1 = ys - y0f, wx1 = xs - x0f;
      float wy0 = 1.f - wy1, wx0 = 1.f - wx1;
      int iy0 = (int)y0f, ix0 = (int)x0f;
      int iy1 = iy0 + 1, ix1 = ix0 + 1;
      float vy0 = (iy0 >= 0 && iy0 <= 63) ? 1.f : 0.f;
      float vy1 = (iy1 >= 0 && iy1 <= 63) ? 1.f : 0.f;
      float vx0 = (ix0 >= 0 && ix0 <= 63) ? 1.f : 0.f;
      float vx1 = (ix1 >= 0 && ix1 <= 63) ? 1.f : 0.f;
      int x0c = min(max(ix0, 0), 63), x1c = min(max(ix1, 0), 63);
      int y0c = min(max(iy0, 0), 63), y1c = min(max(iy1, 0), 63);
      float w00 = wy0 * wx0 * vy0 * vx0;
      float w01 = wy0 * wx1 * vy0 * vx1;
      float w10 = wy1 * wx0 * vy1 * vx0;
      float w11 = wy1 * wx1 * vy1 * vx1;
      int tr0 = min(max(iy0 - (y0 - 2), 0), 5);
      int tr1 = min(max(iy1 - (y0 - 2), 0), 5);
      int c0 = x0c + 2, c1 = x1c + 2;
      f32x2 w00v = {w00, w00}, w01v = {w01, w01};
      f32x2 w10v = {w10, w10}, w11v = {w11, w11};

      bf16x8 frag[4];
#pragma unroll
      for (int ks = 0; ks < 4; ++ks) {
        int c = ks * 2 + kh;
        bf16x8 va = *(const bf16x8*)&ldsx[(tr0 * 68 + c0) * 8 + (c ^ (c0 & 7))];
        bf16x8 vb = *(const bf16x8*)&ldsx[(tr0 * 68 + c1) * 8 + (c ^ (c1 & 7))];
        bf16x8 vc = *(const bf16x8*)&ldsx[(tr1 * 68 + c0) * 8 + (c ^ (c0 & 7))];
        bf16x8 vd = *(const bf16x8*)&ldsx[(tr1 * 68 + c1) * 8 + (c ^ (c1 & 7))];
        frag[ks] = blend4(va, vb, vc, vd, w00v, w01v, w10v, w11v);
      }
      if (!fast) {
        const ushort* p00 = xb + ((size_t)(y0c * XP + x0c + 2)) * 64 + kh * 8;
        const ushort* p01 = xb + ((size_t)(y0c * XP + x1c + 2)) * 64 + kh * 8;
        const ushort* p10 = xb + ((size_t)(y1c * XP + x0c + 2)) * 64 + kh * 8;
        const ushort* p11 = xb + ((size_t)(y1c * XP + x1c + 2)) * 64 + kh * 8;
#pragma unroll
        for (int ks = 0; ks < 4; ++ks) {
          bf16x8 va = *(const bf16x8*)(p00 + ks * 16);
          bf16x8 vb = *(const bf16x8*)(p01 + ks * 16);
          bf16x8 vc = *(const bf16x8*)(p10 + ks * 16);
          bf16x8 vd = *(const bf16x8*)(p11 + ks * 16);
          frag[ks] = blend4(va, vb, vc, vd, w00v, w01v, w10v, w11v);
        }
      }
#pragma unroll
      for (int ks = 0; ks < 4; ++ks) {
        bf16x8 a0 = *(const bf16x8*)&w1F[(size_t)(((kk * 2 + 0) * 4 + ks) * 64 + lane) * 8];
        bf16x8 a1 = *(const bf16x8*)&w1F[(size_t)(((kk * 2 + 1) * 4 + ks) * 64 + lane) * 8];
        accd0 = __builtin_amdgcn_mfma_f32_32x32x16_bf16(a0, frag[ks], accd0, 0, 0, 0);
        accd1 = __builtin_amdgcn_mfma_f32_32x32x16_bf16(a1, frag[ks], accd1, 0, 0, 0);
      }
    }
  }

  // ---------- phase 3: conv 5x5 from LDS (R14 verbatim) ----------
  f32x16 acc50, acc51;
#pragma unroll
  for (int j = 0; j < 16; ++j) { acc50[j] = 0.f; acc51[j] = 0.f; }
  if (interior) {
#pragma unroll
    for (int kk = 0; kk < 25; ++kk) {
      const int ky = kk / 5, kx = kk % 5;
      const int tr = r + ky;
      const int col = px + kx;
      bf16x8 a0[4], a1[4], bfv[4];
#pragma unroll
      for (int ks = 0; ks < 4; ++ks) {
        a0[ks] = *(const bf16x8*)&w3F[(size_t)(((kk * 2 + 0) * 4 + ks) * 64 + lane) * 8];
        a1[ks] = *(const bf16x8*)&w3F[(size_t)(((kk * 2 + 1) * 4 + ks) * 64 + lane) * 8];
      }
#pragma unroll
      for (int ks = 0; ks < 4; ++ks) {
        int c = ks * 2 + kh;
        bfv[ks] = *(const bf16x8*)&ldsx[(tr * 68 + col) * 8 + (c ^ (col & 7))];
      }
#pragma unroll
      for (int ks = 0; ks < 4; ++ks) {
        acc50 = __builtin_amdgcn_mfma_f32_32x32x16_bf16(a0[ks], bfv[ks], acc50, 0, 0, 0);
        acc51 = __builtin_amdgcn_mfma_f32_32x32x16_bf16(a1[ks], bfv[ks], acc51, 0, 0, 0);
      }
    }
  } else {
#pragma unroll
    for (int kk = 0; kk < 25; ++kk) {
      const int ky = kk / 5, kx = kk % 5;
      const int yy = y - 2 + ky;
      if (yy >= 0 && yy <= 63) {  // wave-uniform
        const int tr = r + ky;
        const int col = px + kx;
#pragma unroll
        for (int ks = 0; ks < 4; ++ks) {
          int c = ks * 2 + kh;
          bf16x8 bf = *(const bf16x8*)&ldsx[(tr * 68 + col) * 8 + (c ^ (col & 7))];
          bf16x8 a0 = *(const bf16x8*)&w3F[(size_t)(((kk * 2 + 0) * 4 + ks) * 64 + lane) * 8];
          bf16x8 a1 = *(const bf16x8*)&w3F[(size_t)(((kk * 2 + 1) * 4 + ks) * 64 + lane) * 8];
          acc50 = __builtin_amdgcn_mfma_f32_32x32x16_bf16(a0, bf, acc50, 0, 0, 0);
          acc51 = __builtin_amdgcn_mfma_f32_32x32x16_bf16(a1, bf, acc51, 0, 0, 0);
        }
      }
    }
  }

  // ---------- epilogue ----------
  ushort* op = s1T + ((size_t)((b * 64 + y) * 64 + px)) * 64;
#pragma unroll
  for (int q = 0; q < 4; ++q) {
    int co0 = 8 * q + 4 * kh;
    float vv[4];
#pragma unroll
    for (int rr = 0; rr < 4; ++rr) {
      int co = co0 + rr;
      float vd = accd0[q * 4 + rr] * bn1s[co] + bn1b[co];
      vd = vd > 0.f ? vd : 0.f;
      float v5 = acc50[q * 4 + rr] * bn3s[co] + bn3b[co];
      v5 = v5 > 0.f ? v5 : 0.f;
      vv[rr] = vd + v5;
    }
    ushort4 st;
    st.x = f2bf(vv[0]); st.y = f2bf(vv[1]); st.z = f2bf(vv[2]); st.w = f2bf(vv[3]);
    *(ushort4*)(op + co0) = st;
#pragma unroll
    for (int rr = 0; rr < 4; ++rr) {
      int co = co0 + 32 + rr;
      float vd = accd1[q * 4 + rr] * bn1s[co] + bn1b[co];
      vd = vd > 0.f ? vd : 0.f;
      float v5 = acc51[q * 4 + rr] * bn3s[co] + bn3b[co];
      v5 = v5 > 0.f ? v5 : 0.f;
      vv[rr] = vd + v5;
    }
    st.x = f2bf(vv[0]); st.y = f2bf(vv[1]); st.z = f2bf(vv[2]); st.w = f2bf(vv[3]);
    *(ushort4*)(op + co0 + 32) = st;
  }
}

// ---------------- conv3x3 on s1T + BN2 + residual + ReLU -> out ----------------
// 1-row blocks. Grid (64,16)=1024 blocks, 256 thr = 4 waves (mh, nt).
__global__ __launch_bounds__(256, 2) void conv3_mfma_kernel(
    const ushort* __restrict__ s1T, const ushort* __restrict__ w2F,
    const float* __restrict__ g2, const float* __restrict__ b2,
    const float* __restrict__ m2, const float* __restrict__ v2,
    const float* __restrict__ x, float* __restrict__ out) {
  __shared__ __align__(16) uint4 Bt[3 * 66 * 8];  // 25344 B swizzled
  __shared__ float sc[64], bi[64];
  const int tid = threadIdx.x;
  if (tid < 64) {
    float s = g2[tid] * rsqrtf(v2[tid] + EPSv);
    sc[tid] = s;
    bi[tid] = b2[tid] - m2[tid] * s;
  }
  const int y = blockIdx.x, b = blockIdx.y;
  const int wv = tid >> 6, lane = tid & 63;
  const int ln = lane & 31, kh = lane >> 5;
  const int mh = wv & 1, nt = wv >> 1;
  const int px = nt * 32 + ln;
  const uint4* s1T4 = (const uint4*)s1T;

  for (int i = tid; i < 3 * 66 * 8; i += 256) {
    int tr = i / (66 * 8), rem = i % (66 * 8);
    int col = rem >> 3, c = rem & 7;
    int yy = y - 1 + tr, xcol = col - 1;
    uint4 v = make_uint4(0, 0, 0, 0);
    if (yy >= 0 && yy <= 63 && xcol >= 0 && xcol <= 63)
      v = s1T4[((size_t)((b * 64 + yy) * 64 + xcol)) * 8 + c];
    Bt[(tr * 66 + col) * 8 + (c ^ (col & 7))] = v;
  }
  __syncthreads();

  f32x16 acc;
#pragma unroll
  for (int j = 0; j < 16; ++j) acc[j] = 0.f;

#pragma unroll
  for (int kk = 0; kk < 9; ++kk) {
    const int ky = kk / 3, kx = kk % 3;
    const int col = px + kx;
    bf16x8 af[4], bfr[4];
#pragma unroll
    for (int ccb = 0; ccb < 4; ++ccb)
      af[ccb] = *(const bf16x8*)&w2F[(size_t)(((kk * 2 + mh) * 4 + ccb) * 64 + lane) * 8];
#pragma unroll
    for (int ccb = 0; ccb < 4; ++ccb) {
      int c = ccb * 2 + kh;
      bfr[ccb] = *(const bf16x8*)&Bt[(ky * 66 + col) * 8 + (c ^ (col & 7))];
    }
#pragma unroll
    for (int ccb = 0; ccb < 4; ++ccb)
      acc = __builtin_amdgcn_mfma_f32_32x32x16_bf16(af[ccb], bfr[ccb], acc, 0, 0, 0);
  }
#pragma unroll
  for (int reg = 0; reg < 16; ++reg) {
    int co = (reg & 3) + 8 * (reg >> 2) + 4 * kh + mh * 32;
    size_t o = (((size_t)b * 64 + co) * 64 + y) * 64 + px;
    float v = acc[reg] * sc[co] + bi[co] + x[o];
    out[o] = v > 0.f ? v : 0.f;
  }
}

extern "C" void kernel_launch(void* const* d_in, const int* in_sizes, int n_in,
                              void* d_out, int out_size, void* d_ws, size_t ws_size,
                              hipStream_t stream) {
  const float* x     = (const float*)d_in[0];
  const float* w_off = (const float*)d_in[1];
  const float* b_off = (const float*)d_in[2];
  const float* w1    = (const float*)d_in[3];
  const float* g1    = (const float*)d_in[4];
  const float* b1    = (const float*)d_in[5];
  const float* m1    = (const float*)d_in[6];
  const float* v1    = (const float*)d_in[7];
  const float* w3    = (const float*)d_in[8];
  const float* g3    = (const float*)d_in[9];
  const float* b3    = (const float*)d_in[10];
  const float* m3    = (const float*)d_in[11];
  const float* v3    = (const float*)d_in[12];
  const float* w2    = (const float*)d_in[13];
  const float* g2    = (const float*)d_in[14];
  const float* b2    = (const float*)d_in[15];
  const float* m2    = (const float*)d_in[16];
  const float* v2    = (const float*)d_in[17];
  float* out = (float*)d_out;

  ushort* xTp  = (ushort*)d_ws;                        // 16*64*68*64 = 8.9 MB
  ushort* s1T  = xTp + (size_t)16 * 64 * XP * 64;      // 8.39 MB
  ushort* w3F  = s1T + (size_t)16 * 64 * 64 * 64;      // 102400
  ushort* w2F  = w3F + 102400;                         // 36864
  ushort* w1F  = w2F + 36864;                          // 36864
  ushort* wofF = w1F + 36864;                          // 18432

  prep_kernel<<<dim3(1024 + 760), dim3(256), 0, stream>>>(x, w3, w2, w1, w_off,
                                                          xTp, w3F, w2F, w1F, wofF);
  fused_kernel<<<dim3(32, 16), dim3(256), 0, stream>>>(xTp, wofF, b_off, w1F, w3F,
                                                       g1, b1, m1, v1, g3, b3, m3, v3,
                                                       s1T);
  conv3_mfma_kernel<<<dim3(64, 16), dim3(256), 0, stream>>>(s1T, w2F, g2, b2, m2, v2,
                                                            x, out);
}

// Round 8
// 66.992 us; speedup vs baseline: 1.5897x; 1.0153x over previous
//
#include <hip/hip_runtime.h>
#include <hip/hip_bf16.h>

// BasicBlock9: B=16, CIN=CP=64, H=W=64, K1=3 (deform), K2=5, EPS=1e-5
// R22 = R21 (fused 50.2us, total 68.0us) + two intra-wave ILP changes:
//   (1) conv5 INTERLEAVED into deform in the common superpath
//       (interior && wave-all-fast): per dk, deform kk=dk then 3 (or 2)
//       conv5 kks. MFMA and VALU are separate pipes (m114): conv5 MFMAs
//       fill the pipe during blend4 VALU; blend4 runs under conv5's
//       dependent-MFMA latency. Sequential fallback for edge/mixed.
//   (2) stash LDS round-trip -> 10x __shfl_xor(.,32): offset C-layout
//       co=(reg&3)+8*(reg>>2)+4*kh means px's 18 dy/dx values live in
//       regs 0-9 of lanes ln / ln+32; shuffle replaces 10 ds_writes +
//       18 ds_reads + fence. LDS 62464 -> 53248 B.
//   Still 2 blocks/CU (grid 512 = 2/CU exactly), 256 reg cap: acc 64 +
//   working set ~= 150-190 VGPR, no spill expected (WRITE_SIZE flat).

#define EPSv 1e-5f
#define XP 68  // padded x stride: cols -2..65

typedef __attribute__((ext_vector_type(8))) short bf16x8;
typedef __attribute__((ext_vector_type(16))) float f32x16;
typedef __attribute__((ext_vector_type(2))) float f32x2;

__device__ inline ushort f2bf(float f) {
  __hip_bfloat16 h = __float2bfloat16(f);
  return *(ushort*)&h;
}
__device__ inline float bitsf(unsigned int u) {
  union { unsigned int i; float f; } c; c.i = u; return c.f;
}

// ---------------- prep: transpose x -> padded xTp + fragment-major weights ----------------
__global__ __launch_bounds__(256) void prep_kernel(
    const float* __restrict__ x, const float* __restrict__ w3,
    const float* __restrict__ w2, const float* __restrict__ w1,
    const float* __restrict__ w_off,
    ushort* __restrict__ xTp, ushort* __restrict__ w3F,
    ushort* __restrict__ w2F, ushort* __restrict__ w1F,
    ushort* __restrict__ wofF) {
  __shared__ float tile[64][65];
  const int blk = blockIdx.x;
  if (blk < 1024) {
    const int y = blk & 63, b = blk >> 6;
    for (int i = threadIdx.x; i < 4096; i += 256) {
      int ci = i >> 6, xx = i & 63;
      tile[ci][xx] = x[(((size_t)b * 64 + ci) * 64 + y) * 64 + xx];
    }
    __syncthreads();
    for (int i = threadIdx.x; i < 2048; i += 256) {
      int xx = i >> 5, cip = (i & 31) * 2;
      ushort2 v;
      v.x = f2bf(tile[cip][xx]);
      v.y = f2bf(tile[cip + 1][xx]);
      *(ushort2*)&xTp[(((size_t)(b * 64 + y) * XP) + (xx + 2)) * 64 + cip] = v;
    }
    // zero halo cols {0,1,66,67}
    if (threadIdx.x < 128) {
      int colid = threadIdx.x >> 5;
      int col = (colid & 1) + (colid >> 1) * 66;  // 0,1,66,67
      int cip = (threadIdx.x & 31) * 2;
      ushort2 z; z.x = 0; z.y = 0;
      *(ushort2*)&xTp[(((size_t)(b * 64 + y) * XP) + col) * 64 + cip] = z;
    }
    return;
  }
  int idx = (blk - 1024) * 256 + threadIdx.x;
  if (idx < 102400) {  // w3F
    int j = idx & 7, lane = (idx >> 3) & 63, ks = (idx >> 9) & 3;
    int half = (idx >> 11) & 1, kk = idx >> 12;
    int ln = lane & 31, kh = lane >> 5;
    int co = half * 32 + ln, ci = ks * 16 + kh * 8 + j;
    w3F[idx] = f2bf(w3[(co * 64 + ci) * 25 + kk]);
    return;
  }
  idx -= 102400;
  if (idx < 36864) {  // w2F
    int j = idx & 7, lane = (idx >> 3) & 63, ks = (idx >> 9) & 3;
    int half = (idx >> 11) & 1, kk = idx >> 12;
    int ln = lane & 31, kh = lane >> 5;
    int co = half * 32 + ln, ci = ks * 16 + kh * 8 + j;
    w2F[idx] = f2bf(w2[(co * 64 + ci) * 9 + kk]);
    return;
  }
  idx -= 36864;
  if (idx < 36864) {  // w1F
    int j = idx & 7, lane = (idx >> 3) & 63, ks = (idx >> 9) & 3;
    int half = (idx >> 11) & 1, kk = idx >> 12;
    int ln = lane & 31, kh = lane >> 5;
    int co = half * 32 + ln, ci = ks * 16 + kh * 8 + j;
    w1F[idx] = f2bf(w1[(co * 64 + ci) * 9 + kk]);
    return;
  }
  idx -= 36864;
  if (idx < 18432) {  // wofF
    int j = idx & 7, lane = (idx >> 3) & 63, ks = (idx >> 9) & 3;
    int kk = idx >> 11;
    int ln = lane & 31, kh = lane >> 5;
    int ci = ks * 16 + kh * 8 + j;
    wofF[idx] = f2bf(ln < 18 ? w_off[(ln * 64 + ci) * 9 + kk] : 0.f);
  }
}

// packed bilinear blend of 4 corner bf16x8 frags -> bf16x8
__device__ __forceinline__ bf16x8 blend4(bf16x8 va, bf16x8 vb, bf16x8 vc, bf16x8 vd,
                                         f32x2 w00v, f32x2 w01v, f32x2 w10v, f32x2 w11v) {
  const unsigned int* ua = (const unsigned int*)&va;
  const unsigned int* ub = (const unsigned int*)&vb;
  const unsigned int* uc = (const unsigned int*)&vc;
  const unsigned int* ud = (const unsigned int*)&vd;
  bf16x8 f;
  ushort2* fo = (ushort2*)&f;
#pragma unroll
  for (int d = 0; d < 4; ++d) {
    f32x2 av = {bitsf(ua[d] << 16), bitsf(ua[d] & 0xFFFF0000u)};
    f32x2 bv = {bitsf(ub[d] << 16), bitsf(ub[d] & 0xFFFF0000u)};
    f32x2 cv = {bitsf(uc[d] << 16), bitsf(uc[d] & 0xFFFF0000u)};
    f32x2 dv = {bitsf(ud[d] << 16), bitsf(ud[d] & 0xFFFF0000u)};
    f32x2 r = w00v * av + w01v * bv + w10v * cv + w11v * dv;
    __hip_bfloat162 h2 = __float22bfloat162_rn(make_float2(r.x, r.y));
    fo[d] = *(ushort2*)&h2;
  }
  return f;
}

// ---------------- fused: offset conv + deform + conv5 -> s1T ----------------
// Grid (32, 16), 256 thr = 4 waves: r = wv>>1 (row), nt = wv&1 (px half).
__global__ __launch_bounds__(256, 2) void fused_kernel(
    const ushort* __restrict__ xTp, const ushort* __restrict__ wofF,
    const float* __restrict__ b_off, const ushort* __restrict__ w1F,
    const ushort* __restrict__ w3F,
    const float* __restrict__ g1, const float* __restrict__ b1,
    const float* __restrict__ m1, const float* __restrict__ v1,
    const float* __restrict__ g3, const float* __restrict__ b3,
    const float* __restrict__ m3, const float* __restrict__ v3,
    ushort* __restrict__ s1T) {
  __shared__ __align__(16) uint4 ldsx[6 * 68 * 8];  // 52224 B swizzled tile
  __shared__ float bn1s[64], bn1b[64], bn3s[64], bn3b[64];  // 1024 B

  const int tid = threadIdx.x;
  const int wv = tid >> 6, lane = tid & 63;
  const int ln = lane & 31, kh = lane >> 5;
  const int r = wv >> 1, nt = wv & 1;
  const int y0 = blockIdx.x * 2, b = blockIdx.y;
  const int y = y0 + r, px = nt * 32 + ln;
  const uint4* xT4 = (const uint4*)xTp;
  const ushort* xb = xTp + (size_t)b * 64 * XP * 64;
  const bool interior = (y0 >= 2 && y0 <= 60);  // block-uniform

  if (tid < 64) {
    float s = g1[tid] * rsqrtf(v1[tid] + EPSv);
    bn1s[tid] = s; bn1b[tid] = b1[tid] - m1[tid] * s;
    float s3 = g3[tid] * rsqrtf(v3[tid] + EPSv);
    bn3s[tid] = s3; bn3b[tid] = b3[tid] - m3[tid] * s3;
  }
  // stage rows y0-2..y0+3 (clamped), all 68 padded cols: no bounds branch
  for (int i = tid; i < 6 * 68 * 8; i += 256) {
    int tr = i / (68 * 8), rem = i % (68 * 8);
    int col = rem >> 3, c = rem & 7;
    int ysrc = min(max(y0 - 2 + tr, 0), 63);
    uint4 v = xT4[((size_t)((b * 64 + ysrc) * XP + col)) * 8 + c];
    ldsx[(tr * 68 + col) * 8 + (c ^ (col & 7))] = v;
  }
  __syncthreads();  // B1: tile staged (only barrier in kernel)

  // ---------- phase 1: offset conv 3x3 from LDS ----------
  f32x16 acco;
#pragma unroll
  for (int j = 0; j < 16; ++j) acco[j] = 0.f;
  if (interior) {
#pragma unroll
    for (int kk = 0; kk < 9; ++kk) {
      const int ky = kk / 3, kx = kk % 3;
      const int tr = r + ky + 1;
      const int col = px + kx + 1;
      bf16x8 af[4], bf[4];
#pragma unroll
      for (int ks = 0; ks < 4; ++ks)
        af[ks] = *(const bf16x8*)&wofF[(size_t)((kk * 4 + ks) * 64 + lane) * 8];
#pragma unroll
      for (int ks = 0; ks < 4; ++ks) {
        int c = ks * 2 + kh;
        bf[ks] = *(const bf16x8*)&ldsx[(tr * 68 + col) * 8 + (c ^ (col & 7))];
      }
#pragma unroll
      for (int ks = 0; ks < 4; ++ks)
        acco = __builtin_amdgcn_mfma_f32_32x32x16_bf16(af[ks], bf[ks], acco, 0, 0, 0);
    }
  } else {
#pragma unroll
    for (int kk = 0; kk < 9; ++kk) {
      const int ky = kk / 3, kx = kk % 3;
      const int yy = y - 1 + ky;
      if (yy >= 0 && yy <= 63) {  // wave-uniform
        const int tr = yy - (y0 - 2);
        const int col = px + kx + 1;
#pragma unroll
        for (int ks = 0; ks < 4; ++ks) {
          int c = ks * 2 + kh;
          bf16x8 af = *(const bf16x8*)&wofF[(size_t)((kk * 4 + ks) * 64 + lane) * 8];
          bf16x8 bf = *(const bf16x8*)&ldsx[(tr * 68 + col) * 8 + (c ^ (col & 7))];
          acco = __builtin_amdgcn_mfma_f32_32x32x16_bf16(af, bf, acco, 0, 0, 0);
        }
      }
    }
  }
  // ---------- offset exchange via lane^32 shuffle (no LDS round-trip) ----------
  // C layout: co = (reg&3) + 8*(reg>>2) + 4*kh. px's co 0..17 live in regs
  // 0..9 of lanes ln (kh=0) and ln+32 (kh=1). For co c:
  //   reg = (c&3) + 4*(c>>3), src_kh = (c>>2)&1.
  float oth[10];
#pragma unroll
  for (int t = 0; t < 10; ++t) oth[t] = __shfl_xor(acco[t], 32);
  float dyv[9], dxv[9];
#pragma unroll
  for (int kk = 0; kk < 9; ++kk) {
    const int cY = 2 * kk, cX = 2 * kk + 1;
    const int rY = (cY & 3) + 4 * (cY >> 3);
    const int rX = (cX & 3) + 4 * (cX >> 3);
    const int sY = (cY >> 2) & 1, sX = (cX >> 2) & 1;
    float vy = (sY == kh) ? acco[rY] : oth[rY];
    float vx = (sX == kh) ? acco[rX] : oth[rX];
    dyv[kk] = vy + b_off[cY];
    dxv[kk] = vx + b_off[cX];
  }
  bool fast = true;
#pragma unroll
  for (int kk = 0; kk < 9; ++kk) {
    int iy0 = (int)floorf((float)(y - 1 + kk / 3) + dyv[kk]);
    int iy1 = iy0 + 1;
    bool ok0 = (iy0 < 0) || (iy0 > 63) || (iy0 >= y0 - 2 && iy0 <= y0 + 3);
    bool ok1 = (iy1 < 0) || (iy1 > 63) || (iy1 >= y0 - 2 && iy1 <= y0 + 3);
    fast = fast && ok0 && ok1;
  }
  const bool allfast = (__ballot(!fast) == 0ull);

  // ---------- phase 2+3 ----------
  f32x16 accd0, accd1, acc50, acc51;
#pragma unroll
  for (int j = 0; j < 16; ++j) {
    accd0[j] = 0.f; accd1[j] = 0.f; acc50[j] = 0.f; acc51[j] = 0.f;
  }

  if (interior && allfast) {
    // ======== INTERLEAVED superpath: deform kk=dk + 3(2) conv5 kks ========
#pragma unroll
    for (int dk = 0; dk < 9; ++dk) {
      // ---- deform kk = dk (fast, branch-free) ----
      {
        const int ky = dk / 3, kx = dk % 3;
        float ys = (float)(y - 1 + ky) + dyv[dk];
        float xs = (float)(px - 1 + kx) + dxv[dk];
        float y0f = floorf(ys), x0f = floorf(xs);
        float wy1 = ys - y0f, wx1 = xs - x0f;
        float wy0 = 1.f - wy1, wx0 = 1.f - wx1;
        int iy0 = (int)y0f, ix0 = (int)x0f;
        int iy1 = iy0 + 1, ix1 = ix0 + 1;
        float vy0 = (iy0 >= 0 && iy0 <= 63) ? 1.f : 0.f;
        float vy1 = (iy1 >= 0 && iy1 <= 63) ? 1.f : 0.f;
        float vx0 = (ix0 >= 0 && ix0 <= 63) ? 1.f : 0.f;
        float vx1 = (ix1 >= 0 && ix1 <= 63) ? 1.f : 0.f;
        int x0c = min(max(ix0, 0), 63), x1c = min(max(ix1, 0), 63);
        float w00 = wy0 * wx0 * vy0 * vx0;
        float w01 = wy0 * wx1 * vy0 * vx1;
        float w10 = wy1 * wx0 * vy1 * vx0;
        float w11 = wy1 * wx1 * vy1 * vx1;
        int tr0 = min(max(iy0 - (y0 - 2), 0), 5);
        int tr1 = min(max(iy1 - (y0 - 2), 0), 5);
        int c0 = x0c + 2, c1 = x1c + 2;
        f32x2 w00v = {w00, w00}, w01v = {w01, w01};
        f32x2 w10v = {w10, w10}, w11v = {w11, w11};

        bf16x8 a0[4], a1[4], va[4], vb[4], vc[4], vd[4];
#pragma unroll
        for (int ks = 0; ks < 4; ++ks) {
          a0[ks] = *(const bf16x8*)&w1F[(size_t)(((dk * 2 + 0) * 4 + ks) * 64 + lane) * 8];
          a1[ks] = *(const bf16x8*)&w1F[(size_t)(((dk * 2 + 1) * 4 + ks) * 64 + lane) * 8];
        }
#pragma unroll
        for (int ks = 0; ks < 4; ++ks) {
          int c = ks * 2 + kh;
          va[ks] = *(const bf16x8*)&ldsx[(tr0 * 68 + c0) * 8 + (c ^ (c0 & 7))];
          vb[ks] = *(const bf16x8*)&ldsx[(tr0 * 68 + c1) * 8 + (c ^ (c1 & 7))];
          vc[ks] = *(const bf16x8*)&ldsx[(tr1 * 68 + c0) * 8 + (c ^ (c0 & 7))];
          vd[ks] = *(const bf16x8*)&ldsx[(tr1 * 68 + c1) * 8 + (c ^ (c1 & 7))];
        }
#pragma unroll
        for (int ks = 0; ks < 4; ++ks) {
          bf16x8 f = blend4(va[ks], vb[ks], vc[ks], vd[ks], w00v, w01v, w10v, w11v);
          accd0 = __builtin_amdgcn_mfma_f32_32x32x16_bf16(a0[ks], f, accd0, 0, 0, 0);
          accd1 = __builtin_amdgcn_mfma_f32_32x32x16_bf16(a1[ks], f, accd1, 0, 0, 0);
        }
      }
      // ---- conv5 kks b5..b5+n5-1 (pure MFMA; fills matrix pipe under blend) ----
      const int n5 = (dk < 7) ? 3 : 2;
      const int b5 = (dk < 7) ? dk * 3 : 21 + (dk - 7) * 2;
#pragma unroll
      for (int t = 0; t < 3; ++t) {
        if (t < n5) {
          const int kk = b5 + t;
          const int ky5 = kk / 5, kx5 = kk % 5;
          const int tr = r + ky5;
          const int col = px + kx5;
          bf16x8 a0[4], a1[4], bfv[4];
#pragma unroll
          for (int ks = 0; ks < 4; ++ks) {
            a0[ks] = *(const bf16x8*)&w3F[(size_t)(((kk * 2 + 0) * 4 + ks) * 64 + lane) * 8];
            a1[ks] = *(const bf16x8*)&w3F[(size_t)(((kk * 2 + 1) * 4 + ks) * 64 + lane) * 8];
          }
#pragma unroll
          for (int ks = 0; ks < 4; ++ks) {
            int c = ks * 2 + kh;
            bfv[ks] = *(const bf16x8*)&ldsx[(tr * 68 + col) * 8 + (c ^ (col & 7))];
          }
#pragma unroll
          for (int ks = 0; ks < 4; ++ks) {
            acc50 = __builtin_amdgcn_mfma_f32_32x32x16_bf16(a0[ks], bfv[ks], acc50, 0, 0, 0);
            acc51 = __builtin_amdgcn_mfma_f32_32x32x16_bf16(a1[ks], bfv[ks], acc51, 0, 0, 0);
          }
        }
      }
    }
  } else {
    // ======== sequential fallback (edge rows and/or mixed gather) ========
    if (allfast) {
#pragma unroll
      for (int kk = 0; kk < 9; ++kk) {
        const int ky = kk / 3, kx = kk % 3;
        float ys = (float)(y - 1 + ky) + dyv[kk];
        float xs = (float)(px - 1 + kx) + dxv[kk];
        float y0f = floorf(ys), x0f = floorf(xs);
        float wy1 = ys - y0f, wx1 = xs - x0f;
        float wy0 = 1.f - wy1, wx0 = 1.f - wx1;
        int iy0 = (int)y0f, ix0 = (int)x0f;
        int iy1 = iy0 + 1, ix1 = ix0 + 1;
        float vy0 = (iy0 >= 0 && iy0 <= 63) ? 1.f : 0.f;
        float vy1 = (iy1 >= 0 && iy1 <= 63) ? 1.f : 0.f;
        float vx0 = (ix0 >= 0 && ix0 <= 63) ? 1.f : 0.f;
        float vx1 = (ix1 >= 0 && ix1 <= 63) ? 1.f : 0.f;
        int x0c = min(max(ix0, 0), 63), x1c = min(max(ix1, 0), 63);
        float w00 = wy0 * wx0 * vy0 * vx0;
        float w01 = wy0 * wx1 * vy0 * vx1;
        float w10 = wy1 * wx0 * vy1 * vx0;
        float w11 = wy1 * wx1 * vy1 * vx1;
        int tr0 = min(max(iy0 - (y0 - 2), 0), 5);
        int tr1 = min(max(iy1 - (y0 - 2), 0), 5);
        int c0 = x0c + 2, c1 = x1c + 2;
        f32x2 w00v = {w00, w00}, w01v = {w01, w01};
        f32x2 w10v = {w10, w10}, w11v = {w11, w11};
#pragma unroll
        for (int ks = 0; ks < 4; ++ks) {
          int c = ks * 2 + kh;
          bf16x8 va = *(const bf16x8*)&ldsx[(tr0 * 68 + c0) * 8 + (c ^ (c0 & 7))];
          bf16x8 vb = *(const bf16x8*)&ldsx[(tr0 * 68 + c1) * 8 + (c ^ (c1 & 7))];
          bf16x8 vc = *(const bf16x8*)&ldsx[(tr1 * 68 + c0) * 8 + (c ^ (c0 & 7))];
          bf16x8 vd = *(const bf16x8*)&ldsx[(tr1 * 68 + c1) * 8 + (c ^ (c1 & 7))];
          bf16x8 f = blend4(va, vb, vc, vd, w00v, w01v, w10v, w11v);
          bf16x8 a0 = *(const bf16x8*)&w1F[(size_t)(((kk * 2 + 0) * 4 + ks) * 64 + lane) * 8];
          bf16x8 a1 = *(const bf16x8*)&w1F[(size_t)(((kk * 2 + 1) * 4 + ks) * 64 + lane) * 8];
          accd0 = __builtin_amdgcn_mfma_f32_32x32x16_bf16(a0, f, accd0, 0, 0, 0);
          accd1 = __builtin_amdgcn_mfma_f32_32x32x16_bf16(a1, f, accd1, 0, 0, 0);
        }
      }
    } else {
#pragma unroll
      for (int kk = 0; kk < 9; ++kk) {
        const int ky = kk / 3, kx = kk % 3;
        float ys = (float)(y - 1 + ky) + dyv[kk];
        float xs = (float)(px - 1 + kx) + dxv[kk];
        float y0f = floorf(ys), x0f = floorf(xs);
        float wy1 = ys - y0f, wx1 = xs - x0f;
        float wy0 = 1.f - wy1, wx0 = 1.f - wx1;
        int iy0 = (int)y0f, ix0 = (int)x0f;
        int iy1 = iy0 + 1, ix1 = ix0 + 1;
        float vy0 = (iy0 >= 0 && iy0 <= 63) ? 1.f : 0.f;
        float vy1 = (iy1 >= 0 && iy1 <= 63) ? 1.f : 0.f;
        float vx0 = (ix0 >= 0 && ix0 <= 63) ? 1.f : 0.f;
        float vx1 = (ix1 >= 0 && ix1 <= 63) ? 1.f : 0.f;
        int x0c = min(max(ix0, 0), 63), x1c = min(max(ix1, 0), 63);
        int y0c = min(max(iy0, 0), 63), y1c = min(max(iy1, 0), 63);
        float w00 = wy0 * wx0 * vy0 * vx0;
        float w01 = wy0 * wx1 * vy0 * vx1;
        float w10 = wy1 * wx0 * vy1 * vx0;
        float w11 = wy1 * wx1 * vy1 * vx1;
        int tr0 = min(max(iy0 - (y0 - 2), 0), 5);
        int tr1 = min(max(iy1 - (y0 - 2), 0), 5);
        int c0 = x0c + 2, c1 = x1c + 2;
        f32x2 w00v = {w00, w00}, w01v = {w01, w01};
        f32x2 w10v = {w10, w10}, w11v = {w11, w11};

        bf16x8 frag[4];
#pragma unroll
        for (int ks = 0; ks < 4; ++ks) {
          int c = ks * 2 + kh;
          bf16x8 va = *(const bf16x8*)&ldsx[(tr0 * 68 + c0) * 8 + (c ^ (c0 & 7))];
          bf16x8 vb = *(const bf16x8*)&ldsx[(tr0 * 68 + c1) * 8 + (c ^ (c1 & 7))];
          bf16x8 vc = *(const bf16x8*)&ldsx[(tr1 * 68 + c0) * 8 + (c ^ (c0 & 7))];
          bf16x8 vd = *(const bf16x8*)&ldsx[(tr1 * 68 + c1) * 8 + (c ^ (c1 & 7))];
          frag[ks] = blend4(va, vb, vc, vd, w00v, w01v, w10v, w11v);
        }
        if (!fast) {
          const ushort* p00 = xb + ((size_t)(y0c * XP + x0c + 2)) * 64 + kh * 8;
          const ushort* p01 = xb + ((size_t)(y0c * XP + x1c + 2)) * 64 + kh * 8;
          const ushort* p10 = xb + ((size_t)(y1c * XP + x0c + 2)) * 64 + kh * 8;
          const ushort* p11 = xb + ((size_t)(y1c * XP + x1c + 2)) * 64 + kh * 8;
#pragma unroll
          for (int ks = 0; ks < 4; ++ks) {
            bf16x8 va = *(const bf16x8*)(p00 + ks * 16);
            bf16x8 vb = *(const bf16x8*)(p01 + ks * 16);
            bf16x8 vc = *(const bf16x8*)(p10 + ks * 16);
            bf16x8 vd = *(const bf16x8*)(p11 + ks * 16);
            frag[ks] = blend4(va, vb, vc, vd, w00v, w01v, w10v, w11v);
          }
        }
#pragma unroll
        for (int ks = 0; ks < 4; ++ks) {
          bf16x8 a0 = *(const bf16x8*)&w1F[(size_t)(((kk * 2 + 0) * 4 + ks) * 64 + lane) * 8];
          bf16x8 a1 = *(const bf16x8*)&w1F[(size_t)(((kk * 2 + 1) * 4 + ks) * 64 + lane) * 8];
          accd0 = __builtin_amdgcn_mfma_f32_32x32x16_bf16(a0, frag[ks], accd0, 0, 0, 0);
          accd1 = __builtin_amdgcn_mfma_f32_32x32x16_bf16(a1, frag[ks], accd1, 0, 0, 0);
        }
      }
    }
    // conv5 sequential
    if (interior) {
#pragma unroll
      for (int kk = 0; kk < 25; ++kk) {
        const int ky = kk / 5, kx = kk % 5;
        const int tr = r + ky;
        const int col = px + kx;
        bf16x8 a0[4], a1[4], bfv[4];
#pragma unroll
        for (int ks = 0; ks < 4; ++ks) {
          a0[ks] = *(const bf16x8*)&w3F[(size_t)(((kk * 2 + 0) * 4 + ks) * 64 + lane) * 8];
          a1[ks] = *(const bf16x8*)&w3F[(size_t)(((kk * 2 + 1) * 4 + ks) * 64 + lane) * 8];
        }
#pragma unroll
        for (int ks = 0; ks < 4; ++ks) {
          int c = ks * 2 + kh;
          bfv[ks] = *(const bf16x8*)&ldsx[(tr * 68 + col) * 8 + (c ^ (col & 7))];
        }
#pragma unroll
        for (int ks = 0; ks < 4; ++ks) {
          acc50 = __builtin_amdgcn_mfma_f32_32x32x16_bf16(a0[ks], bfv[ks], acc50, 0, 0, 0);
          acc51 = __builtin_amdgcn_mfma_f32_32x32x16_bf16(a1[ks], bfv[ks], acc51, 0, 0, 0);
        }
      }
    } else {
#pragma unroll
      for (int kk = 0; kk < 25; ++kk) {
        const int ky = kk / 5, kx = kk % 5;
        const int yy = y - 2 + ky;
        if (yy >= 0 && yy <= 63) {  // wave-uniform
          const int tr = r + ky;
          const int col = px + kx;
#pragma unroll
          for (int ks = 0; ks < 4; ++ks) {
            int c = ks * 2 + kh;
            bf16x8 bf = *(const bf16x8*)&ldsx[(tr * 68 + col) * 8 + (c ^ (col & 7))];
            bf16x8 a0 = *(const bf16x8*)&w3F[(size_t)(((kk * 2 + 0) * 4 + ks) * 64 + lane) * 8];
            bf16x8 a1 = *(const bf16x8*)&w3F[(size_t)(((kk * 2 + 1) * 4 + ks) * 64 + lane) * 8];
            acc50 = __builtin_amdgcn_mfma_f32_32x32x16_bf16(a0, bf, acc50, 0, 0, 0);
            acc51 = __builtin_amdgcn_mfma_f32_32x32x16_bf16(a1, bf, acc51, 0, 0, 0);
          }
        }
      }
    }
  }

  // ---------- epilogue ----------
  ushort* op = s1T + ((size_t)((b * 64 + y) * 64 + px)) * 64;
#pragma unroll
  for (int q = 0; q < 4; ++q) {
    int co0 = 8 * q + 4 * kh;
    float vv[4];
#pragma unroll
    for (int rr = 0; rr < 4; ++rr) {
      int co = co0 + rr;
      float vd = accd0[q * 4 + rr] * bn1s[co] + bn1b[co];
      vd = vd > 0.f ? vd : 0.f;
      float v5 = acc50[q * 4 + rr] * bn3s[co] + bn3b[co];
      v5 = v5 > 0.f ? v5 : 0.f;
      vv[rr] = vd + v5;
    }
    ushort4 st;
    st.x = f2bf(vv[0]); st.y = f2bf(vv[1]); st.z = f2bf(vv[2]); st.w = f2bf(vv[3]);
    *(ushort4*)(op + co0) = st;
#pragma unroll
    for (int rr = 0; rr < 4; ++rr) {
      int co = co0 + 32 + rr;
      float vd = accd1[q * 4 + rr] * bn1s[co] + bn1b[co];
      vd = vd > 0.f ? vd : 0.f;
      float v5 = acc51[q * 4 + rr] * bn3s[co] + bn3b[co];
      v5 = v5 > 0.f ? v5 : 0.f;
      vv[rr] = vd + v5;
    }
    st.x = f2bf(vv[0]); st.y = f2bf(vv[1]); st.z = f2bf(vv[2]); st.w = f2bf(vv[3]);
    *(ushort4*)(op + co0 + 32) = st;
  }
}

// ---------------- conv3x3 on s1T + BN2 + residual + ReLU -> out ----------------
// 1-row blocks. Grid (64,16)=1024 blocks, 256 thr = 4 waves (mh, nt).
__global__ __launch_bounds__(256, 2) void conv3_mfma_kernel(
    const ushort* __restrict__ s1T, const ushort* __restrict__ w2F,
    const float* __restrict__ g2, const float* __restrict__ b2,
    const float* __restrict__ m2, const float* __restrict__ v2,
    const float* __restrict__ x, float* __restrict__ out) {
  __shared__ __align__(16) uint4 Bt[3 * 66 * 8];  // 25344 B swizzled
  __shared__ float sc[64], bi[64];
  const int tid = threadIdx.x;
  if (tid < 64) {
    float s = g2[tid] * rsqrtf(v2[tid] + EPSv);
    sc[tid] = s;
    bi[tid] = b2[tid] - m2[tid] * s;
  }
  const int y = blockIdx.x, b = blockIdx.y;
  const int wv = tid >> 6, lane = tid & 63;
  const int ln = lane & 31, kh = lane >> 5;
  const int mh = wv & 1, nt = wv >> 1;
  const int px = nt * 32 + ln;
  const uint4* s1T4 = (const uint4*)s1T;

  for (int i = tid; i < 3 * 66 * 8; i += 256) {
    int tr = i / (66 * 8), rem = i % (66 * 8);
    int col = rem >> 3, c = rem & 7;
    int yy = y - 1 + tr, xcol = col - 1;
    uint4 v = make_uint4(0, 0, 0, 0);
    if (yy >= 0 && yy <= 63 && xcol >= 0 && xcol <= 63)
      v = s1T4[((size_t)((b * 64 + yy) * 64 + xcol)) * 8 + c];
    Bt[(tr * 66 + col) * 8 + (c ^ (col & 7))] = v;
  }
  __syncthreads();

  f32x16 acc;
#pragma unroll
  for (int j = 0; j < 16; ++j) acc[j] = 0.f;

#pragma unroll
  for (int kk = 0; kk < 9; ++kk) {
    const int ky = kk / 3, kx = kk % 3;
    const int col = px + kx;
    bf16x8 af[4], bfr[4];
#pragma unroll
    for (int ccb = 0; ccb < 4; ++ccb)
      af[ccb] = *(const bf16x8*)&w2F[(size_t)(((kk * 2 + mh) * 4 + ccb) * 64 + lane) * 8];
#pragma unroll
    for (int ccb = 0; ccb < 4; ++ccb) {
      int c = ccb * 2 + kh;
      bfr[ccb] = *(const bf16x8*)&Bt[(ky * 66 + col) * 8 + (c ^ (col & 7))];
    }
#pragma unroll
    for (int ccb = 0; ccb < 4; ++ccb)
      acc = __builtin_amdgcn_mfma_f32_32x32x16_bf16(af[ccb], bfr[ccb], acc, 0, 0, 0);
  }
#pragma unroll
  for (int reg = 0; reg < 16; ++reg) {
    int co = (reg & 3) + 8 * (reg >> 2) + 4 * kh + mh * 32;
    size_t o = (((size_t)b * 64 + co) * 64 + y) * 64 + px;
    float v = acc[reg] * sc[co] + bi[co] + x[o];
    out[o] = v > 0.f ? v : 0.f;
  }
}

extern "C" void kernel_launch(void* const* d_in, const int* in_sizes, int n_in,
                              void* d_out, int out_size, void* d_ws, size_t ws_size,
                              hipStream_t stream) {
  const float* x     = (const float*)d_in[0];
  const float* w_off = (const float*)d_in[1];
  const float* b_off = (const float*)d_in[2];
  const float* w1    = (const float*)d_in[3];
  const float* g1    = (const float*)d_in[4];
  const float* b1    = (const float*)d_in[5];
  const float* m1    = (const float*)d_in[6];
  const float* v1    = (const float*)d_in[7];
  const float* w3    = (const float*)d_in[8];
  const float* g3    = (const float*)d_in[9];
  const float* b3    = (const float*)d_in[10];
  const float* m3    = (const float*)d_in[11];
  const float* v3    = (const float*)d_in[12];
  const float* w2    = (const float*)d_in[13];
  const float* g2    = (const float*)d_in[14];
  const float* b2    = (const float*)d_in[15];
  const float* m2    = (const float*)d_in[16];
  const float* v2    = (const float*)d_in[17];
  float* out = (float*)d_out;

  ushort* xTp  = (ushort*)d_ws;                        // 16*64*68*64 = 8.9 MB
  ushort* s1T  = xTp + (size_t)16 * 64 * XP * 64;      // 8.39 MB
  ushort* w3F  = s1T + (size_t)16 * 64 * 64 * 64;      // 102400
  ushort* w2F  = w3F + 102400;                         // 36864
  ushort* w1F  = w2F + 36864;                          // 36864
  ushort* wofF = w1F + 36864;                          // 18432

  prep_kernel<<<dim3(1024 + 760), dim3(256), 0, stream>>>(x, w3, w2, w1, w_off,
                                                          xTp, w3F, w2F, w1F, wofF);
  fused_kernel<<<dim3(32, 16), dim3(256), 0, stream>>>(xTp, wofF, b_off, w1F, w3F,
                                                       g1, b1, m1, v1, g3, b3, m3, v3,
                                                       s1T);
  conv3_mfma_kernel<<<dim3(64, 16), dim3(256), 0, stream>>>(s1T, w2F, g2, b2, m2, v2,
                                                            x, out);
}

// Round 9
// 62.542 us; speedup vs baseline: 1.7028x; 1.0712x over previous
//
#include <hip/hip_runtime.h>
#include <hip/hip_bf16.h>

// BasicBlock9: B=16, CIN=CP=64, H=W=64, K1=3 (deform), K2=5, EPS=1e-5
// R23 = R22 (fused 48.6us, total 67.0us) with the staged pipeline switched
//   bf16 -> fp16. Why: blend4 was ~68 VALU ops/blend x 36 blends on the
//   LDS->MFMA critical chain, all unpack/repack because data was bf16.
//   fp16 blend = 16x v_pk_fma_f16 ops (packed, no unpack). fp16 mantissa
//   (10b) > bf16 (7b) -> accuracy improves; range fine (x~N(0,1), small
//   weights). MFMA -> mfma_f32_32x32x16_f16 (same rate, same C/D layout).
//   Structure unchanged from R22: interleaved superpath, shuffle offset
//   exchange, single barrier, 2 blocks/CU.

#define EPSv 1e-5f
#define XP 68  // padded x stride: cols -2..65

typedef _Float16 f16x2 __attribute__((ext_vector_type(2)));
typedef _Float16 f16x8 __attribute__((ext_vector_type(8)));
typedef __attribute__((ext_vector_type(16))) float f32x16;

__device__ inline ushort f2h(float f) {
  _Float16 h = (_Float16)f;
  return *(ushort*)&h;
}

// ---------------- prep: transpose x -> padded xTp (f16) + fragment-major weights ----------------
__global__ __launch_bounds__(256) void prep_kernel(
    const float* __restrict__ x, const float* __restrict__ w3,
    const float* __restrict__ w2, const float* __restrict__ w1,
    const float* __restrict__ w_off,
    ushort* __restrict__ xTp, ushort* __restrict__ w3F,
    ushort* __restrict__ w2F, ushort* __restrict__ w1F,
    ushort* __restrict__ wofF) {
  __shared__ float tile[64][65];
  const int blk = blockIdx.x;
  if (blk < 1024) {
    const int y = blk & 63, b = blk >> 6;
    for (int i = threadIdx.x; i < 4096; i += 256) {
      int ci = i >> 6, xx = i & 63;
      tile[ci][xx] = x[(((size_t)b * 64 + ci) * 64 + y) * 64 + xx];
    }
    __syncthreads();
    for (int i = threadIdx.x; i < 2048; i += 256) {
      int xx = i >> 5, cip = (i & 31) * 2;
      ushort2 v;
      v.x = f2h(tile[cip][xx]);
      v.y = f2h(tile[cip + 1][xx]);
      *(ushort2*)&xTp[(((size_t)(b * 64 + y) * XP) + (xx + 2)) * 64 + cip] = v;
    }
    // zero halo cols {0,1,66,67}
    if (threadIdx.x < 128) {
      int colid = threadIdx.x >> 5;
      int col = (colid & 1) + (colid >> 1) * 66;  // 0,1,66,67
      int cip = (threadIdx.x & 31) * 2;
      ushort2 z; z.x = 0; z.y = 0;
      *(ushort2*)&xTp[(((size_t)(b * 64 + y) * XP) + col) * 64 + cip] = z;
    }
    return;
  }
  int idx = (blk - 1024) * 256 + threadIdx.x;
  if (idx < 102400) {  // w3F
    int j = idx & 7, lane = (idx >> 3) & 63, ks = (idx >> 9) & 3;
    int half = (idx >> 11) & 1, kk = idx >> 12;
    int ln = lane & 31, kh = lane >> 5;
    int co = half * 32 + ln, ci = ks * 16 + kh * 8 + j;
    w3F[idx] = f2h(w3[(co * 64 + ci) * 25 + kk]);
    return;
  }
  idx -= 102400;
  if (idx < 36864) {  // w2F
    int j = idx & 7, lane = (idx >> 3) & 63, ks = (idx >> 9) & 3;
    int half = (idx >> 11) & 1, kk = idx >> 12;
    int ln = lane & 31, kh = lane >> 5;
    int co = half * 32 + ln, ci = ks * 16 + kh * 8 + j;
    w2F[idx] = f2h(w2[(co * 64 + ci) * 9 + kk]);
    return;
  }
  idx -= 36864;
  if (idx < 36864) {  // w1F
    int j = idx & 7, lane = (idx >> 3) & 63, ks = (idx >> 9) & 3;
    int half = (idx >> 11) & 1, kk = idx >> 12;
    int ln = lane & 31, kh = lane >> 5;
    int co = half * 32 + ln, ci = ks * 16 + kh * 8 + j;
    w1F[idx] = f2h(w1[(co * 64 + ci) * 9 + kk]);
    return;
  }
  idx -= 36864;
  if (idx < 18432) {  // wofF
    int j = idx & 7, lane = (idx >> 3) & 63, ks = (idx >> 9) & 3;
    int kk = idx >> 11;
    int ln = lane & 31, kh = lane >> 5;
    int ci = ks * 16 + kh * 8 + j;
    wofF[idx] = f2h(ln < 18 ? w_off[(ln * 64 + ci) * 9 + kk] : 0.f);
  }
}

// packed fp16 bilinear blend of 4 corner f16x8 frags -> f16x8 (v_pk_fma_f16)
__device__ __forceinline__ f16x8 blend4(f16x8 va, f16x8 vb, f16x8 vc, f16x8 vd,
                                        f16x2 w00, f16x2 w01, f16x2 w10, f16x2 w11) {
  const f16x2* a = (const f16x2*)&va;
  const f16x2* b = (const f16x2*)&vb;
  const f16x2* c = (const f16x2*)&vc;
  const f16x2* d = (const f16x2*)&vd;
  f16x8 f;
  f16x2* fo = (f16x2*)&f;
#pragma unroll
  for (int i = 0; i < 4; ++i)
    fo[i] = a[i] * w00 + b[i] * w01 + c[i] * w10 + d[i] * w11;
  return f;
}

// ---------------- fused: offset conv + deform + conv5 -> s1T ----------------
// Grid (32, 16), 256 thr = 4 waves: r = wv>>1 (row), nt = wv&1 (px half).
__global__ __launch_bounds__(256, 2) void fused_kernel(
    const ushort* __restrict__ xTp, const ushort* __restrict__ wofF,
    const float* __restrict__ b_off, const ushort* __restrict__ w1F,
    const ushort* __restrict__ w3F,
    const float* __restrict__ g1, const float* __restrict__ b1,
    const float* __restrict__ m1, const float* __restrict__ v1,
    const float* __restrict__ g3, const float* __restrict__ b3,
    const float* __restrict__ m3, const float* __restrict__ v3,
    ushort* __restrict__ s1T) {
  __shared__ __align__(16) uint4 ldsx[6 * 68 * 8];  // 52224 B swizzled tile
  __shared__ float bn1s[64], bn1b[64], bn3s[64], bn3b[64];  // 1024 B

  const int tid = threadIdx.x;
  const int wv = tid >> 6, lane = tid & 63;
  const int ln = lane & 31, kh = lane >> 5;
  const int r = wv >> 1, nt = wv & 1;
  const int y0 = blockIdx.x * 2, b = blockIdx.y;
  const int y = y0 + r, px = nt * 32 + ln;
  const uint4* xT4 = (const uint4*)xTp;
  const ushort* xb = xTp + (size_t)b * 64 * XP * 64;
  const bool interior = (y0 >= 2 && y0 <= 60);  // block-uniform

  if (tid < 64) {
    float s = g1[tid] * rsqrtf(v1[tid] + EPSv);
    bn1s[tid] = s; bn1b[tid] = b1[tid] - m1[tid] * s;
    float s3 = g3[tid] * rsqrtf(v3[tid] + EPSv);
    bn3s[tid] = s3; bn3b[tid] = b3[tid] - m3[tid] * s3;
  }
  // stage rows y0-2..y0+3 (clamped), all 68 padded cols: no bounds branch
  for (int i = tid; i < 6 * 68 * 8; i += 256) {
    int tr = i / (68 * 8), rem = i % (68 * 8);
    int col = rem >> 3, c = rem & 7;
    int ysrc = min(max(y0 - 2 + tr, 0), 63);
    uint4 v = xT4[((size_t)((b * 64 + ysrc) * XP + col)) * 8 + c];
    ldsx[(tr * 68 + col) * 8 + (c ^ (col & 7))] = v;
  }
  __syncthreads();  // B1: tile staged (only barrier in kernel)

  // ---------- phase 1: offset conv 3x3 from LDS ----------
  f32x16 acco;
#pragma unroll
  for (int j = 0; j < 16; ++j) acco[j] = 0.f;
  if (interior) {
#pragma unroll
    for (int kk = 0; kk < 9; ++kk) {
      const int ky = kk / 3, kx = kk % 3;
      const int tr = r + ky + 1;
      const int col = px + kx + 1;
      f16x8 af[4], bf[4];
#pragma unroll
      for (int ks = 0; ks < 4; ++ks)
        af[ks] = *(const f16x8*)&wofF[(size_t)((kk * 4 + ks) * 64 + lane) * 8];
#pragma unroll
      for (int ks = 0; ks < 4; ++ks) {
        int c = ks * 2 + kh;
        bf[ks] = *(const f16x8*)&ldsx[(tr * 68 + col) * 8 + (c ^ (col & 7))];
      }
#pragma unroll
      for (int ks = 0; ks < 4; ++ks)
        acco = __builtin_amdgcn_mfma_f32_32x32x16_f16(af[ks], bf[ks], acco, 0, 0, 0);
    }
  } else {
#pragma unroll
    for (int kk = 0; kk < 9; ++kk) {
      const int ky = kk / 3, kx = kk % 3;
      const int yy = y - 1 + ky;
      if (yy >= 0 && yy <= 63) {  // wave-uniform
        const int tr = yy - (y0 - 2);
        const int col = px + kx + 1;
#pragma unroll
        for (int ks = 0; ks < 4; ++ks) {
          int c = ks * 2 + kh;
          f16x8 af = *(const f16x8*)&wofF[(size_t)((kk * 4 + ks) * 64 + lane) * 8];
          f16x8 bf = *(const f16x8*)&ldsx[(tr * 68 + col) * 8 + (c ^ (col & 7))];
          acco = __builtin_amdgcn_mfma_f32_32x32x16_f16(af, bf, acco, 0, 0, 0);
        }
      }
    }
  }
  // ---------- offset exchange via lane^32 shuffle (no LDS round-trip) ----------
  // C layout: co = (reg&3) + 8*(reg>>2) + 4*kh. px's co 0..17 live in regs
  // 0..9 of lanes ln (kh=0) and ln+32 (kh=1). For co c:
  //   reg = (c&3) + 4*(c>>3), src_kh = (c>>2)&1.
  float oth[10];
#pragma unroll
  for (int t = 0; t < 10; ++t) oth[t] = __shfl_xor(acco[t], 32);
  float dyv[9], dxv[9];
#pragma unroll
  for (int kk = 0; kk < 9; ++kk) {
    const int cY = 2 * kk, cX = 2 * kk + 1;
    const int rY = (cY & 3) + 4 * (cY >> 3);
    const int rX = (cX & 3) + 4 * (cX >> 3);
    const int sY = (cY >> 2) & 1, sX = (cX >> 2) & 1;
    float vy = (sY == kh) ? acco[rY] : oth[rY];
    float vx = (sX == kh) ? acco[rX] : oth[rX];
    dyv[kk] = vy + b_off[cY];
    dxv[kk] = vx + b_off[cX];
  }
  bool fast = true;
#pragma unroll
  for (int kk = 0; kk < 9; ++kk) {
    int iy0 = (int)floorf((float)(y - 1 + kk / 3) + dyv[kk]);
    int iy1 = iy0 + 1;
    bool ok0 = (iy0 < 0) || (iy0 > 63) || (iy0 >= y0 - 2 && iy0 <= y0 + 3);
    bool ok1 = (iy1 < 0) || (iy1 > 63) || (iy1 >= y0 - 2 && iy1 <= y0 + 3);
    fast = fast && ok0 && ok1;
  }
  const bool allfast = (__ballot(!fast) == 0ull);

  // ---------- phase 2+3 ----------
  f32x16 accd0, accd1, acc50, acc51;
#pragma unroll
  for (int j = 0; j < 16; ++j) {
    accd0[j] = 0.f; accd1[j] = 0.f; acc50[j] = 0.f; acc51[j] = 0.f;
  }

  if (interior && allfast) {
    // ======== INTERLEAVED superpath: deform kk=dk + 3(2) conv5 kks ========
#pragma unroll
    for (int dk = 0; dk < 9; ++dk) {
      // ---- deform kk = dk (fast, branch-free) ----
      {
        const int ky = dk / 3, kx = dk % 3;
        float ys = (float)(y - 1 + ky) + dyv[dk];
        float xs = (float)(px - 1 + kx) + dxv[dk];
        float y0f = floorf(ys), x0f = floorf(xs);
        float wy1 = ys - y0f, wx1 = xs - x0f;
        float wy0 = 1.f - wy1, wx0 = 1.f - wx1;
        int iy0 = (int)y0f, ix0 = (int)x0f;
        int iy1 = iy0 + 1, ix1 = ix0 + 1;
        float vy0 = (iy0 >= 0 && iy0 <= 63) ? 1.f : 0.f;
        float vy1 = (iy1 >= 0 && iy1 <= 63) ? 1.f : 0.f;
        float vx0 = (ix0 >= 0 && ix0 <= 63) ? 1.f : 0.f;
        float vx1 = (ix1 >= 0 && ix1 <= 63) ? 1.f : 0.f;
        int x0c = min(max(ix0, 0), 63), x1c = min(max(ix1, 0), 63);
        float w00 = wy0 * wx0 * vy0 * vx0;
        float w01 = wy0 * wx1 * vy0 * vx1;
        float w10 = wy1 * wx0 * vy1 * vx0;
        float w11 = wy1 * wx1 * vy1 * vx1;
        int tr0 = min(max(iy0 - (y0 - 2), 0), 5);
        int tr1 = min(max(iy1 - (y0 - 2), 0), 5);
        int c0 = x0c + 2, c1 = x1c + 2;
        f16x2 w00v = {(_Float16)w00, (_Float16)w00};
        f16x2 w01v = {(_Float16)w01, (_Float16)w01};
        f16x2 w10v = {(_Float16)w10, (_Float16)w10};
        f16x2 w11v = {(_Float16)w11, (_Float16)w11};

        f16x8 a0[4], a1[4], va[4], vb[4], vc[4], vd[4];
#pragma unroll
        for (int ks = 0; ks < 4; ++ks) {
          a0[ks] = *(const f16x8*)&w1F[(size_t)(((dk * 2 + 0) * 4 + ks) * 64 + lane) * 8];
          a1[ks] = *(const f16x8*)&w1F[(size_t)(((dk * 2 + 1) * 4 + ks) * 64 + lane) * 8];
        }
#pragma unroll
        for (int ks = 0; ks < 4; ++ks) {
          int c = ks * 2 + kh;
          va[ks] = *(const f16x8*)&ldsx[(tr0 * 68 + c0) * 8 + (c ^ (c0 & 7))];
          vb[ks] = *(const f16x8*)&ldsx[(tr0 * 68 + c1) * 8 + (c ^ (c1 & 7))];
          vc[ks] = *(const f16x8*)&ldsx[(tr1 * 68 + c0) * 8 + (c ^ (c0 & 7))];
          vd[ks] = *(const f16x8*)&ldsx[(tr1 * 68 + c1) * 8 + (c ^ (c1 & 7))];
        }
#pragma unroll
        for (int ks = 0; ks < 4; ++ks) {
          f16x8 f = blend4(va[ks], vb[ks], vc[ks], vd[ks], w00v, w01v, w10v, w11v);
          accd0 = __builtin_amdgcn_mfma_f32_32x32x16_f16(a0[ks], f, accd0, 0, 0, 0);
          accd1 = __builtin_amdgcn_mfma_f32_32x32x16_f16(a1[ks], f, accd1, 0, 0, 0);
        }
      }
      // ---- conv5 kks b5..b5+n5-1 (pure MFMA; fills matrix pipe under blend) ----
      const int n5 = (dk < 7) ? 3 : 2;
      const int b5 = (dk < 7) ? dk * 3 : 21 + (dk - 7) * 2;
#pragma unroll
      for (int t = 0; t < 3; ++t) {
        if (t < n5) {
          const int kk = b5 + t;
          const int ky5 = kk / 5, kx5 = kk % 5;
          const int tr = r + ky5;
          const int col = px + kx5;
          f16x8 a0[4], a1[4], bfv[4];
#pragma unroll
          for (int ks = 0; ks < 4; ++ks) {
            a0[ks] = *(const f16x8*)&w3F[(size_t)(((kk * 2 + 0) * 4 + ks) * 64 + lane) * 8];
            a1[ks] = *(const f16x8*)&w3F[(size_t)(((kk * 2 + 1) * 4 + ks) * 64 + lane) * 8];
          }
#pragma unroll
          for (int ks = 0; ks < 4; ++ks) {
            int c = ks * 2 + kh;
            bfv[ks] = *(const f16x8*)&ldsx[(tr * 68 + col) * 8 + (c ^ (col & 7))];
          }
#pragma unroll
          for (int ks = 0; ks < 4; ++ks) {
            acc50 = __builtin_amdgcn_mfma_f32_32x32x16_f16(a0[ks], bfv[ks], acc50, 0, 0, 0);
            acc51 = __builtin_amdgcn_mfma_f32_32x32x16_f16(a1[ks], bfv[ks], acc51, 0, 0, 0);
          }
        }
      }
    }
  } else {
    // ======== sequential fallback (edge rows and/or mixed gather) ========
    if (allfast) {
#pragma unroll
      for (int kk = 0; kk < 9; ++kk) {
        const int ky = kk / 3, kx = kk % 3;
        float ys = (float)(y - 1 + ky) + dyv[kk];
        float xs = (float)(px - 1 + kx) + dxv[kk];
        float y0f = floorf(ys), x0f = floorf(xs);
        float wy1 = ys - y0f, wx1 = xs - x0f;
        float wy0 = 1.f - wy1, wx0 = 1.f - wx1;
        int iy0 = (int)y0f, ix0 = (int)x0f;
        int iy1 = iy0 + 1, ix1 = ix0 + 1;
        float vy0 = (iy0 >= 0 && iy0 <= 63) ? 1.f : 0.f;
        float vy1 = (iy1 >= 0 && iy1 <= 63) ? 1.f : 0.f;
        float vx0 = (ix0 >= 0 && ix0 <= 63) ? 1.f : 0.f;
        float vx1 = (ix1 >= 0 && ix1 <= 63) ? 1.f : 0.f;
        int x0c = min(max(ix0, 0), 63), x1c = min(max(ix1, 0), 63);
        float w00 = wy0 * wx0 * vy0 * vx0;
        float w01 = wy0 * wx1 * vy0 * vx1;
        float w10 = wy1 * wx0 * vy1 * vx0;
        float w11 = wy1 * wx1 * vy1 * vx1;
        int tr0 = min(max(iy0 - (y0 - 2), 0), 5);
        int tr1 = min(max(iy1 - (y0 - 2), 0), 5);
        int c0 = x0c + 2, c1 = x1c + 2;
        f16x2 w00v = {(_Float16)w00, (_Float16)w00};
        f16x2 w01v = {(_Float16)w01, (_Float16)w01};
        f16x2 w10v = {(_Float16)w10, (_Float16)w10};
        f16x2 w11v = {(_Float16)w11, (_Float16)w11};
#pragma unroll
        for (int ks = 0; ks < 4; ++ks) {
          int c = ks * 2 + kh;
          f16x8 va = *(const f16x8*)&ldsx[(tr0 * 68 + c0) * 8 + (c ^ (c0 & 7))];
          f16x8 vb = *(const f16x8*)&ldsx[(tr0 * 68 + c1) * 8 + (c ^ (c1 & 7))];
          f16x8 vc = *(const f16x8*)&ldsx[(tr1 * 68 + c0) * 8 + (c ^ (c0 & 7))];
          f16x8 vd = *(const f16x8*)&ldsx[(tr1 * 68 + c1) * 8 + (c ^ (c1 & 7))];
          f16x8 f = blend4(va, vb, vc, vd, w00v, w01v, w10v, w11v);
          f16x8 a0 = *(const f16x8*)&w1F[(size_t)(((kk * 2 + 0) * 4 + ks) * 64 + lane) * 8];
          f16x8 a1 = *(const f16x8*)&w1F[(size_t)(((kk * 2 + 1) * 4 + ks) * 64 + lane) * 8];
          accd0 = __builtin_amdgcn_mfma_f32_32x32x16_f16(a0, f, accd0, 0, 0, 0);
          accd1 = __builtin_amdgcn_mfma_f32_32x32x16_f16(a1, f, accd1, 0, 0, 0);
        }
      }
    } else {
#pragma unroll
      for (int kk = 0; kk < 9; ++kk) {
        const int ky = kk / 3, kx = kk % 3;
        float ys = (float)(y - 1 + ky) + dyv[kk];
        float xs = (float)(px - 1 + kx) + dxv[kk];
        float y0f = floorf(ys), x0f = floorf(xs);
        float wy1 = ys - y0f, wx1 = xs - x0f;
        float wy0 = 1.f - wy1, wx0 = 1.f - wx1;
        int iy0 = (int)y0f, ix0 = (int)x0f;
        int iy1 = iy0 + 1, ix1 = ix0 + 1;
        float vy0 = (iy0 >= 0 && iy0 <= 63) ? 1.f : 0.f;
        float vy1 = (iy1 >= 0 && iy1 <= 63) ? 1.f : 0.f;
        float vx0 = (ix0 >= 0 && ix0 <= 63) ? 1.f : 0.f;
        float vx1 = (ix1 >= 0 && ix1 <= 63) ? 1.f : 0.f;
        int x0c = min(max(ix0, 0), 63), x1c = min(max(ix1, 0), 63);
        int y0c = min(max(iy0, 0), 63), y1c = min(max(iy1, 0), 63);
        float w00 = wy0 * wx0 * vy0 * vx0;
        float w01 = wy0 * wx1 * vy0 * vx1;
        float w10 = wy1 * wx0 * vy1 * vx0;
        float w11 = wy1 * wx1 * vy1 * vx1;
        int tr0 = min(max(iy0 - (y0 - 2), 0), 5);
        int tr1 = min(max(iy1 - (y0 - 2), 0), 5);
        int c0 = x0c + 2, c1 = x1c + 2;
        f16x2 w00v = {(_Float16)w00, (_Float16)w00};
        f16x2 w01v = {(_Float16)w01, (_Float16)w01};
        f16x2 w10v = {(_Float16)w10, (_Float16)w10};
        f16x2 w11v = {(_Float16)w11, (_Float16)w11};

        f16x8 frag[4];
#pragma unroll
        for (int ks = 0; ks < 4; ++ks) {
          int c = ks * 2 + kh;
          f16x8 va = *(const f16x8*)&ldsx[(tr0 * 68 + c0) * 8 + (c ^ (c0 & 7))];
          f16x8 vb = *(const f16x8*)&ldsx[(tr0 * 68 + c1) * 8 + (c ^ (c1 & 7))];
          f16x8 vc = *(const f16x8*)&ldsx[(tr1 * 68 + c0) * 8 + (c ^ (c0 & 7))];
          f16x8 vd = *(const f16x8*)&ldsx[(tr1 * 68 + c1) * 8 + (c ^ (c1 & 7))];
          frag[ks] = blend4(va, vb, vc, vd, w00v, w01v, w10v, w11v);
        }
        if (!fast) {
          const ushort* p00 = xb + ((size_t)(y0c * XP + x0c + 2)) * 64 + kh * 8;
          const ushort* p01 = xb + ((size_t)(y0c * XP + x1c + 2)) * 64 + kh * 8;
          const ushort* p10 = xb + ((size_t)(y1c * XP + x0c + 2)) * 64 + kh * 8;
          const ushort* p11 = xb + ((size_t)(y1c * XP + x1c + 2)) * 64 + kh * 8;
#pragma unroll
          for (int ks = 0; ks < 4; ++ks) {
            f16x8 va = *(const f16x8*)(p00 + ks * 16);
            f16x8 vb = *(const f16x8*)(p01 + ks * 16);
            f16x8 vc = *(const f16x8*)(p10 + ks * 16);
            f16x8 vd = *(const f16x8*)(p11 + ks * 16);
            frag[ks] = blend4(va, vb, vc, vd, w00v, w01v, w10v, w11v);
          }
        }
#pragma unroll
        for (int ks = 0; ks < 4; ++ks) {
          f16x8 a0 = *(const f16x8*)&w1F[(size_t)(((kk * 2 + 0) * 4 + ks) * 64 + lane) * 8];
          f16x8 a1 = *(const f16x8*)&w1F[(size_t)(((kk * 2 + 1) * 4 + ks) * 64 + lane) * 8];
          accd0 = __builtin_amdgcn_mfma_f32_32x32x16_f16(a0, frag[ks], accd0, 0, 0, 0);
          accd1 = __builtin_amdgcn_mfma_f32_32x32x16_f16(a1, frag[ks], accd1, 0, 0, 0);
        }
      }
    }
    // conv5 sequential
    if (interior) {
#pragma unroll
      for (int kk = 0; kk < 25; ++kk) {
        const int ky = kk / 5, kx = kk % 5;
        const int tr = r + ky;
        const int col = px + kx;
        f16x8 a0[4], a1[4], bfv[4];
#pragma unroll
        for (int ks = 0; ks < 4; ++ks) {
          a0[ks] = *(const f16x8*)&w3F[(size_t)(((kk * 2 + 0) * 4 + ks) * 64 + lane) * 8];
          a1[ks] = *(const f16x8*)&w3F[(size_t)(((kk * 2 + 1) * 4 + ks) * 64 + lane) * 8];
        }
#pragma unroll
        for (int ks = 0; ks < 4; ++ks) {
          int c = ks * 2 + kh;
          bfv[ks] = *(const f16x8*)&ldsx[(tr * 68 + col) * 8 + (c ^ (col & 7))];
        }
#pragma unroll
        for (int ks = 0; ks < 4; ++ks) {
          acc50 = __builtin_amdgcn_mfma_f32_32x32x16_f16(a0[ks], bfv[ks], acc50, 0, 0, 0);
          acc51 = __builtin_amdgcn_mfma_f32_32x32x16_f16(a1[ks], bfv[ks], acc51, 0, 0, 0);
        }
      }
    } else {
#pragma unroll
      for (int kk = 0; kk < 25; ++kk) {
        const int ky = kk / 5, kx = kk % 5;
        const int yy = y - 2 + ky;
        if (yy >= 0 && yy <= 63) {  // wave-uniform
          const int tr = r + ky;
          const int col = px + kx;
#pragma unroll
          for (int ks = 0; ks < 4; ++ks) {
            int c = ks * 2 + kh;
            f16x8 bf = *(const f16x8*)&ldsx[(tr * 68 + col) * 8 + (c ^ (col & 7))];
            f16x8 a0 = *(const f16x8*)&w3F[(size_t)(((kk * 2 + 0) * 4 + ks) * 64 + lane) * 8];
            f16x8 a1 = *(const f16x8*)&w3F[(size_t)(((kk * 2 + 1) * 4 + ks) * 64 + lane) * 8];
            acc50 = __builtin_amdgcn_mfma_f32_32x32x16_f16(a0, bf, acc50, 0, 0, 0);
            acc51 = __builtin_amdgcn_mfma_f32_32x32x16_f16(a1, bf, acc51, 0, 0, 0);
          }
        }
      }
    }
  }

  // ---------- epilogue ----------
  ushort* op = s1T + ((size_t)((b * 64 + y) * 64 + px)) * 64;
#pragma unroll
  for (int q = 0; q < 4; ++q) {
    int co0 = 8 * q + 4 * kh;
    float vv[4];
#pragma unroll
    for (int rr = 0; rr < 4; ++rr) {
      int co = co0 + rr;
      float vd = accd0[q * 4 + rr] * bn1s[co] + bn1b[co];
      vd = vd > 0.f ? vd : 0.f;
      float v5 = acc50[q * 4 + rr] * bn3s[co] + bn3b[co];
      v5 = v5 > 0.f ? v5 : 0.f;
      vv[rr] = vd + v5;
    }
    ushort4 st;
    st.x = f2h(vv[0]); st.y = f2h(vv[1]); st.z = f2h(vv[2]); st.w = f2h(vv[3]);
    *(ushort4*)(op + co0) = st;
#pragma unroll
    for (int rr = 0; rr < 4; ++rr) {
      int co = co0 + 32 + rr;
      float vd = accd1[q * 4 + rr] * bn1s[co] + bn1b[co];
      vd = vd > 0.f ? vd : 0.f;
      float v5 = acc51[q * 4 + rr] * bn3s[co] + bn3b[co];
      v5 = v5 > 0.f ? v5 : 0.f;
      vv[rr] = vd + v5;
    }
    st.x = f2h(vv[0]); st.y = f2h(vv[1]); st.z = f2h(vv[2]); st.w = f2h(vv[3]);
    *(ushort4*)(op + co0 + 32) = st;
  }
}

// ---------------- conv3x3 on s1T + BN2 + residual + ReLU -> out ----------------
// 1-row blocks. Grid (64,16)=1024 blocks, 256 thr = 4 waves (mh, nt).
__global__ __launch_bounds__(256, 2) void conv3_mfma_kernel(
    const ushort* __restrict__ s1T, const ushort* __restrict__ w2F,
    const float* __restrict__ g2, const float* __restrict__ b2,
    const float* __restrict__ m2, const float* __restrict__ v2,
    const float* __restrict__ x, float* __restrict__ out) {
  __shared__ __align__(16) uint4 Bt[3 * 66 * 8];  // 25344 B swizzled
  __shared__ float sc[64], bi[64];
  const int tid = threadIdx.x;
  if (tid < 64) {
    float s = g2[tid] * rsqrtf(v2[tid] + EPSv);
    sc[tid] = s;
    bi[tid] = b2[tid] - m2[tid] * s;
  }
  const int y = blockIdx.x, b = blockIdx.y;
  const int wv = tid >> 6, lane = tid & 63;
  const int ln = lane & 31, kh = lane >> 5;
  const int mh = wv & 1, nt = wv >> 1;
  const int px = nt * 32 + ln;
  const uint4* s1T4 = (const uint4*)s1T;

  for (int i = tid; i < 3 * 66 * 8; i += 256) {
    int tr = i / (66 * 8), rem = i % (66 * 8);
    int col = rem >> 3, c = rem & 7;
    int yy = y - 1 + tr, xcol = col - 1;
    uint4 v = make_uint4(0, 0, 0, 0);
    if (yy >= 0 && yy <= 63 && xcol >= 0 && xcol <= 63)
      v = s1T4[((size_t)((b * 64 + yy) * 64 + xcol)) * 8 + c];
    Bt[(tr * 66 + col) * 8 + (c ^ (col & 7))] = v;
  }
  __syncthreads();

  f32x16 acc;
#pragma unroll
  for (int j = 0; j < 16; ++j) acc[j] = 0.f;

#pragma unroll
  for (int kk = 0; kk < 9; ++kk) {
    const int ky = kk / 3, kx = kk % 3;
    const int col = px + kx;
    f16x8 af[4], bfr[4];
#pragma unroll
    for (int ccb = 0; ccb < 4; ++ccb)
      af[ccb] = *(const f16x8*)&w2F[(size_t)(((kk * 2 + mh) * 4 + ccb) * 64 + lane) * 8];
#pragma unroll
    for (int ccb = 0; ccb < 4; ++ccb) {
      int c = ccb * 2 + kh;
      bfr[ccb] = *(const f16x8*)&Bt[(ky * 66 + col) * 8 + (c ^ (col & 7))];
    }
#pragma unroll
    for (int ccb = 0; ccb < 4; ++ccb)
      acc = __builtin_amdgcn_mfma_f32_32x32x16_f16(af[ccb], bfr[ccb], acc, 0, 0, 0);
  }
#pragma unroll
  for (int reg = 0; reg < 16; ++reg) {
    int co = (reg & 3) + 8 * (reg >> 2) + 4 * kh + mh * 32;
    size_t o = (((size_t)b * 64 + co) * 64 + y) * 64 + px;
    float v = acc[reg] * sc[co] + bi[co] + x[o];
    out[o] = v > 0.f ? v : 0.f;
  }
}

extern "C" void kernel_launch(void* const* d_in, const int* in_sizes, int n_in,
                              void* d_out, int out_size, void* d_ws, size_t ws_size,
                              hipStream_t stream) {
  const float* x     = (const float*)d_in[0];
  const float* w_off = (const float*)d_in[1];
  const float* b_off = (const float*)d_in[2];
  const float* w1    = (const float*)d_in[3];
  const float* g1    = (const float*)d_in[4];
  const float* b1    = (const float*)d_in[5];
  const float* m1    = (const float*)d_in[6];
  const float* v1    = (const float*)d_in[7];
  const float* w3    = (const float*)d_in[8];
  const float* g3    = (const float*)d_in[9];
  const float* b3    = (const float*)d_in[10];
  const float* m3    = (const float*)d_in[11];
  const float* v3    = (const float*)d_in[12];
  const float* w2    = (const float*)d_in[13];
  const float* g2    = (const float*)d_in[14];
  const float* b2    = (const float*)d_in[15];
  const float* m2    = (const float*)d_in[16];
  const float* v2    = (const float*)d_in[17];
  float* out = (float*)d_out;

  ushort* xTp  = (ushort*)d_ws;                        // 16*64*68*64 = 8.9 MB
  ushort* s1T  = xTp + (size_t)16 * 64 * XP * 64;      // 8.39 MB
  ushort* w3F  = s1T + (size_t)16 * 64 * 64 * 64;      // 102400
  ushort* w2F  = w3F + 102400;                         // 36864
  ushort* w1F  = w2F + 36864;                          // 36864
  ushort* wofF = w1F + 36864;                          // 18432

  prep_kernel<<<dim3(1024 + 760), dim3(256), 0, stream>>>(x, w3, w2, w1, w_off,
                                                          xTp, w3F, w2F, w1F, wofF);
  fused_kernel<<<dim3(32, 16), dim3(256), 0, stream>>>(xTp, wofF, b_off, w1F, w3F,
                                                       g1, b1, m1, v1, g3, b3, m3, v3,
                                                       s1T);
  conv3_mfma_kernel<<<dim3(64, 16), dim3(256), 0, stream>>>(s1T, w2F, g2, b2, m2, v2,
                                                            x, out);
}